// Round 11
// baseline (354.473 us; speedup 1.0000x reference)
//
#include <hip/hip_runtime.h>

#define TS 500      // n_patch (sequence length)
#define NB 16       // batch
#define NROW 8000   // NB * TS
#define DMODEL 256
#define NHEAD 8
#define HDIM 32
#define FFD 1024

typedef __bf16 bf16x8 __attribute__((ext_vector_type(8)));
typedef __bf16 bf16x4 __attribute__((ext_vector_type(4)));
typedef float  f32x4  __attribute__((ext_vector_type(4)));
typedef float  f32x2  __attribute__((ext_vector_type(2)));

__device__ __forceinline__ float wred_sum(float v) {
    #pragma unroll
    for (int off = 32; off; off >>= 1) v += __shfl_xor(v, off, 64);
    return v;
}

// A-fragment scatter store: element (grow, col) of an [8000][K] bf16 matrix
// packed as KS=K/32 fragments.
__device__ __forceinline__ void pa_store(__bf16* __restrict__ PA, int KS,
                                         int grow, int col, float y) {
    int mt = grow >> 4, rl = grow & 15;
    size_t idx = ((size_t)(mt * KS + (col >> 5)) * 64 + ((col >> 3) & 3) * 16 + rl) * 8 + (col & 7);
    PA[idx] = (__bf16)y;
}

// ---------------------------------------------------------------------------
// All weight packs in ONE kernel. Flat grid of 1616 blocks, range dispatch.
// ---------------------------------------------------------------------------
__global__ __launch_bounds__(256) void k_pack_all(
    const float* __restrict__ qkv_w, const float* __restrict__ out_w,
    const float* __restrict__ ff1_w, const float* __restrict__ ff2_w,
    const float* __restrict__ proj_w, const float* __restrict__ op_w,
    __bf16* __restrict__ PBq, __bf16* __restrict__ PBo,
    __bf16* __restrict__ PB1, __bf16* __restrict__ PB2,
    __bf16* __restrict__ PBp, __bf16* __restrict__ PBop)
{
    int bid = blockIdx.x;
    const float* W; __bf16* PB; int KS, NT, wLS, pLS, l, bx;
    if (bid < 384)       { W = qkv_w;  PB = PBq;  KS = 8;  NT = 48; wLS = 196608; pLS = 196608; l = bid / 96;          bx = bid % 96; }
    else if (bid < 512)  { W = out_w;  PB = PBo;  KS = 8;  NT = 16; wLS = 65536;  pLS = 65536;  l = (bid - 384) / 32;  bx = (bid - 384) % 32; }
    else if (bid < 1024) { W = ff1_w;  PB = PB1;  KS = 8;  NT = 64; wLS = 262144; pLS = 262144; l = (bid - 512) / 128; bx = (bid - 512) % 128; }
    else if (bid < 1536) { W = ff2_w;  PB = PB2;  KS = 32; NT = 16; wLS = 262144; pLS = 262144; l = (bid - 1024) / 128; bx = (bid - 1024) % 128; }
    else if (bid < 1600) { W = proj_w; PB = PBp;  KS = 16; NT = 16; wLS = 0;      pLS = 0;      l = 0;                 bx = bid - 1536; }
    else                 { W = op_w;   PB = PBop; KS = 8;  NT = 8;  wLS = 0;      pLS = 0;      l = 0;                 bx = bid - 1600; }

    int gid = bx * 256 + threadIdx.x;
    if (gid >= NT * KS * 64) return;
    int lane = gid & 63;
    int ks = (gid >> 6) % KS;
    int nt = (gid >> 6) / KS;
    int N = NT * 16;
    int k0 = ks * 32 + (lane >> 4) * 8;
    int col = nt * 16 + (lane & 15);
    const float* src = W + (size_t)l * wLS;
    bf16x8 v;
    #pragma unroll
    for (int j = 0; j < 8; j++) v[j] = (__bf16)src[(size_t)(k0 + j) * N + col];
    *(bf16x8*)(PB + (size_t)l * pLS + ((size_t)(nt * KS + ks) * 64 + lane) * 8) = v;
}

// ---------------------------------------------------------------------------
// Patch stage FUSED: gather 4x128 -> 512, LN1(512), A-frags to LDS,
// MFMA GEMM 512->256, + bias + LN2 -> h, + LN_attn0 -> PA. 32 rows/block.
// ---------------------------------------------------------------------------
__global__ __launch_bounds__(256) void k_patchfused(
    const float* __restrict__ x, const float* __restrict__ g1, const float* __restrict__ b1,
    const __bf16* __restrict__ PBp, const float* __restrict__ bias,
    float* __restrict__ h, __bf16* __restrict__ PAout,
    const float* __restrict__ gam, const float* __restrict__ bet,
    const float* __restrict__ gam2, const float* __restrict__ bet2)
{
    __shared__ __align__(16) __bf16 As[2][16][64][8];   // 32 KB
    __shared__ float redS[4][32];
    __shared__ float redQ[4][32];
    int t = threadIdx.x, lane = t & 63, w = t >> 6;
    int row0 = blockIdx.x * 32;

    for (int rr = 0; rr < 8; rr++) {
        int lrow = w * 8 + rr;
        int row = row0 + lrow;
        int b = row / TS, p = row - b * TS;
        int kb = lane * 8;
        const float* src = x + ((size_t)(p * 4 + (kb >> 7)) * NB + b) * 128 + (kb & 127);
        float4 lo = *(const float4*)src;
        float4 hi = *(const float4*)(src + 4);
        float v[8] = {lo.x, lo.y, lo.z, lo.w, hi.x, hi.y, hi.z, hi.w};
        float s = 0.f;
        #pragma unroll
        for (int j = 0; j < 8; j++) s += v[j];
        s = wred_sum(s);
        float mu = s * (1.0f / 512.0f);
        float q = 0.f;
        #pragma unroll
        for (int j = 0; j < 8; j++) { float d = v[j] - mu; q += d * d; }
        q = wred_sum(q);
        float rs = rsqrtf(q * (1.0f / 512.0f) + 1e-6f);
        float4 gl = *(const float4*)(g1 + kb), gh = *(const float4*)(g1 + kb + 4);
        float4 bl = *(const float4*)(b1 + kb), bh = *(const float4*)(b1 + kb + 4);
        float gg[8] = {gl.x, gl.y, gl.z, gl.w, gh.x, gh.y, gh.z, gh.w};
        float bbv[8] = {bl.x, bl.y, bl.z, bl.w, bh.x, bh.y, bh.z, bh.w};
        bf16x8 yv;
        #pragma unroll
        for (int j = 0; j < 8; j++) yv[j] = (__bf16)((v[j] - mu) * rs * gg[j] + bbv[j]);
        *(bf16x8*)&As[lrow >> 4][lane >> 2][(lane & 3) * 16 + (lrow & 15)][0] = yv;
    }
    __syncthreads();

    const bf16x8* B8 = (const bf16x8*)PBp;
    f32x4 acc[2][4] = {};
    #pragma unroll 8
    for (int ks = 0; ks < 16; ks++) {
        bf16x8 a0 = *(const bf16x8*)&As[0][ks][lane][0];
        bf16x8 a1 = *(const bf16x8*)&As[1][ks][lane][0];
        #pragma unroll
        for (int n = 0; n < 4; n++) {
            bf16x8 b = B8[((size_t)(w * 4 + n) * 16 + ks) * 64 + lane];
            acc[0][n] = __builtin_amdgcn_mfma_f32_16x16x32_bf16(a0, b, acc[0][n], 0, 0, 0);
            acc[1][n] = __builtin_amdgcn_mfma_f32_16x16x32_bf16(a1, b, acc[1][n], 0, 0, 0);
        }
    }

    int g_ = lane >> 4, cl = lane & 15;
    int rbase = g_ * 4;
    int mt0 = blockIdx.x * 2;
    float gamv[4], betv[4], gam2v[4], bet2v[4];
    #pragma unroll
    for (int n = 0; n < 4; n++) {
        int col = (w * 4 + n) * 16 + cl;
        float bv = bias[col];
        gamv[n] = gam[col]; betv[n] = bet[col];
        gam2v[n] = gam2[col]; bet2v[n] = bet2[col];
        #pragma unroll
        for (int m = 0; m < 2; m++)
            #pragma unroll
            for (int r = 0; r < 4; r++) acc[m][n][r] += bv;
    }
    float mu[2][4], rstd[2][4];
    {
        float ps[2][4];
        #pragma unroll
        for (int m = 0; m < 2; m++)
            #pragma unroll
            for (int r = 0; r < 4; r++) {
                float s = acc[m][0][r] + acc[m][1][r] + acc[m][2][r] + acc[m][3][r];
                #pragma unroll
                for (int off = 1; off < 16; off <<= 1) s += __shfl_xor(s, off, 64);
                ps[m][r] = s;
            }
        if (cl == 0)
            #pragma unroll
            for (int m = 0; m < 2; m++)
                #pragma unroll
                for (int r = 0; r < 4; r++) redS[w][m * 16 + rbase + r] = ps[m][r];
        __syncthreads();
        #pragma unroll
        for (int m = 0; m < 2; m++)
            #pragma unroll
            for (int r = 0; r < 4; r++) {
                int lr = m * 16 + rbase + r;
                mu[m][r] = (redS[0][lr] + redS[1][lr] + redS[2][lr] + redS[3][lr]) * (1.0f / 256.0f);
            }
        float pq[2][4];
        #pragma unroll
        for (int m = 0; m < 2; m++)
            #pragma unroll
            for (int r = 0; r < 4; r++) {
                float s = 0.f;
                #pragma unroll
                for (int n = 0; n < 4; n++) { float d = acc[m][n][r] - mu[m][r]; s += d * d; }
                #pragma unroll
                for (int off = 1; off < 16; off <<= 1) s += __shfl_xor(s, off, 64);
                pq[m][r] = s;
            }
        if (cl == 0)
            #pragma unroll
            for (int m = 0; m < 2; m++)
                #pragma unroll
                for (int r = 0; r < 4; r++) redQ[w][m * 16 + rbase + r] = pq[m][r];
        __syncthreads();
        #pragma unroll
        for (int m = 0; m < 2; m++)
            #pragma unroll
            for (int r = 0; r < 4; r++) {
                int lr = m * 16 + rbase + r;
                float var = (redQ[0][lr] + redQ[1][lr] + redQ[2][lr] + redQ[3][lr]) * (1.0f / 256.0f);
                rstd[m][r] = rsqrtf(var + 1e-6f);
            }
    }
    float ps2[2][4];
    #pragma unroll
    for (int m = 0; m < 2; m++) {
        int row = (mt0 + m) * 16 + rbase;
        #pragma unroll
        for (int r = 0; r < 4; r++) {
            float s = 0.f;
            #pragma unroll
            for (int n = 0; n < 4; n++) {
                int col = (w * 4 + n) * 16 + cl;
                float y1 = (acc[m][n][r] - mu[m][r]) * rstd[m][r] * gamv[n] + betv[n];
                h[(size_t)(row + r) * 256 + col] = y1;
                s += y1;
            }
            #pragma unroll
            for (int off = 1; off < 16; off <<= 1) s += __shfl_xor(s, off, 64);
            ps2[m][r] = s;
        }
    }
    if (cl == 0)
        #pragma unroll
        for (int m = 0; m < 2; m++)
            #pragma unroll
            for (int r = 0; r < 4; r++) redS[w][m * 16 + rbase + r] = ps2[m][r];
    __syncthreads();
    float mu2[2][4], rstd2[2][4];
    #pragma unroll
    for (int m = 0; m < 2; m++)
        #pragma unroll
        for (int r = 0; r < 4; r++) {
            int lr = m * 16 + rbase + r;
            mu2[m][r] = (redS[0][lr] + redS[1][lr] + redS[2][lr] + redS[3][lr]) * (1.0f / 256.0f);
        }
    float pq2[2][4];
    #pragma unroll
    for (int m = 0; m < 2; m++)
        #pragma unroll
        for (int r = 0; r < 4; r++) {
            float s = 0.f;
            #pragma unroll
            for (int n = 0; n < 4; n++) {
                float y1 = (acc[m][n][r] - mu[m][r]) * rstd[m][r] * gamv[n] + betv[n];
                float d = y1 - mu2[m][r];
                s += d * d;
            }
            #pragma unroll
            for (int off = 1; off < 16; off <<= 1) s += __shfl_xor(s, off, 64);
            pq2[m][r] = s;
        }
    if (cl == 0)
        #pragma unroll
        for (int m = 0; m < 2; m++)
            #pragma unroll
            for (int r = 0; r < 4; r++) redQ[w][m * 16 + rbase + r] = pq2[m][r];
    __syncthreads();
    #pragma unroll
    for (int m = 0; m < 2; m++)
        #pragma unroll
        for (int r = 0; r < 4; r++) {
            int lr = m * 16 + rbase + r;
            float var = (redQ[0][lr] + redQ[1][lr] + redQ[2][lr] + redQ[3][lr]) * (1.0f / 256.0f);
            rstd2[m][r] = rsqrtf(var + 1e-5f);
        }
    #pragma unroll
    for (int m = 0; m < 2; m++) {
        int row = (mt0 + m) * 16 + rbase;
        #pragma unroll
        for (int n = 0; n < 4; n++) {
            int col = (w * 4 + n) * 16 + cl;
            #pragma unroll
            for (int r = 0; r < 4; r++) {
                float y1 = (acc[m][n][r] - mu[m][r]) * rstd[m][r] * gamv[n] + betv[n];
                float y2 = (y1 - mu2[m][r]) * rstd2[m][r] * gam2v[n] + bet2v[n];
                pa_store(PAout, 8, row + r, col, y2);
            }
        }
    }
}

// ---------------------------------------------------------------------------
// MFMA GEMM: C[8000][N] = A[8000][K] * B[K][N] (+epilogue).
// EPI 0: dstb[row*768+col] = bf16(acc+bias)              (qkv bf16)
// EPI 4: h += acc+bias -> dst fp32; LN(h)->PA            (residual; NTW=4,gridY=1)
// EPI 5: dst[(p*NB+b)*128+col] = acc+bias (swapaxes out) (final)
// ---------------------------------------------------------------------------
template<int KS, int MT, int NTW, int EPI>
__global__ __launch_bounds__(256) void k_gemm(
    const __bf16* __restrict__ PA, const __bf16* __restrict__ PB,
    const float* __restrict__ bias, float* __restrict__ dst,
    __bf16* __restrict__ dstb,
    const float* __restrict__ gam, const float* __restrict__ bet)
{
    int t = threadIdx.x, lane = t & 63, w = t >> 6;
    int mt0 = blockIdx.x * MT;
    int ntBase = blockIdx.y * (4 * NTW) + w * NTW;

    const bf16x8* A8 = (const bf16x8*)PA;
    const bf16x8* B8 = (const bf16x8*)PB;

    f32x4 acc[MT][NTW] = {};

    #pragma unroll 8
    for (int ks = 0; ks < KS; ks++) {
        bf16x8 a[MT], b[NTW];
        #pragma unroll
        for (int m = 0; m < MT; m++)
            a[m] = A8[((size_t)(mt0 + m) * KS + ks) * 64 + lane];
        #pragma unroll
        for (int n = 0; n < NTW; n++)
            b[n] = B8[((size_t)(ntBase + n) * KS + ks) * 64 + lane];
        #pragma unroll
        for (int m = 0; m < MT; m++)
            #pragma unroll
            for (int n = 0; n < NTW; n++)
                acc[m][n] = __builtin_amdgcn_mfma_f32_16x16x32_bf16(a[m], b[n], acc[m][n], 0, 0, 0);
    }

    int g_ = lane >> 4, cl = lane & 15;
    int rbase = g_ * 4;

    if constexpr (EPI == 4) {
        __shared__ float redS[4][MT * 16];
        __shared__ float redQ[4][MT * 16];
        float gamv[NTW], betv[NTW];
        #pragma unroll
        for (int n = 0; n < NTW; n++) {
            int col = (ntBase + n) * 16 + cl;
            float bv = bias[col];
            gamv[n] = gam[col]; betv[n] = bet[col];
            #pragma unroll
            for (int m = 0; m < MT; m++) {
                int row = (mt0 + m) * 16 + rbase;
                #pragma unroll
                for (int r = 0; r < 4; r++) {
                    float v = acc[m][n][r] + bv + dst[(size_t)(row + r) * 256 + col];
                    dst[(size_t)(row + r) * 256 + col] = v;
                    acc[m][n][r] = v;
                }
            }
        }
        float mu[MT][4], rstd[MT][4];
        {
            float ps[MT][4];
            #pragma unroll
            for (int m = 0; m < MT; m++)
                #pragma unroll
                for (int r = 0; r < 4; r++) {
                    float s = 0.f;
                    #pragma unroll
                    for (int n = 0; n < NTW; n++) s += acc[m][n][r];
                    #pragma unroll
                    for (int off = 1; off < 16; off <<= 1) s += __shfl_xor(s, off, 64);
                    ps[m][r] = s;
                }
            if (cl == 0)
                #pragma unroll
                for (int m = 0; m < MT; m++)
                    #pragma unroll
                    for (int r = 0; r < 4; r++) redS[w][m * 16 + rbase + r] = ps[m][r];
            __syncthreads();
            #pragma unroll
            for (int m = 0; m < MT; m++)
                #pragma unroll
                for (int r = 0; r < 4; r++) {
                    int lr = m * 16 + rbase + r;
                    mu[m][r] = (redS[0][lr] + redS[1][lr] + redS[2][lr] + redS[3][lr]) * (1.0f / 256.0f);
                }
            float pq[MT][4];
            #pragma unroll
            for (int m = 0; m < MT; m++)
                #pragma unroll
                for (int r = 0; r < 4; r++) {
                    float s = 0.f;
                    #pragma unroll
                    for (int n = 0; n < NTW; n++) { float d = acc[m][n][r] - mu[m][r]; s += d * d; }
                    #pragma unroll
                    for (int off = 1; off < 16; off <<= 1) s += __shfl_xor(s, off, 64);
                    pq[m][r] = s;
                }
            if (cl == 0)
                #pragma unroll
                for (int m = 0; m < MT; m++)
                    #pragma unroll
                    for (int r = 0; r < 4; r++) redQ[w][m * 16 + rbase + r] = pq[m][r];
            __syncthreads();
            #pragma unroll
            for (int m = 0; m < MT; m++)
                #pragma unroll
                for (int r = 0; r < 4; r++) {
                    int lr = m * 16 + rbase + r;
                    float var = (redQ[0][lr] + redQ[1][lr] + redQ[2][lr] + redQ[3][lr]) * (1.0f / 256.0f);
                    rstd[m][r] = rsqrtf(var + 1e-5f);
                }
        }
        #pragma unroll
        for (int m = 0; m < MT; m++) {
            int row = (mt0 + m) * 16 + rbase;
            #pragma unroll
            for (int n = 0; n < NTW; n++) {
                int col = (ntBase + n) * 16 + cl;
                #pragma unroll
                for (int r = 0; r < 4; r++) {
                    float y = (acc[m][n][r] - mu[m][r]) * rstd[m][r] * gamv[n] + betv[n];
                    pa_store(dstb, 8, row + r, col, y);
                }
            }
        }
    } else {
        #pragma unroll
        for (int m = 0; m < MT; m++) {
            int row = (mt0 + m) * 16 + rbase;
            #pragma unroll
            for (int n = 0; n < NTW; n++) {
                int col = (ntBase + n) * 16 + cl;
                float bv = bias[col];
                f32x4 v = acc[m][n];
                if (EPI == 0) {
                    #pragma unroll
                    for (int r = 0; r < 4; r++)
                        dstb[(size_t)(row + r) * 768 + col] = (__bf16)(v[r] + bv);
                } else {  // EPI == 5: swapaxes output write
                    #pragma unroll
                    for (int r = 0; r < 4; r++) {
                        int grow = row + r;
                        int bq = grow / TS, p = grow - bq * TS;
                        dst[((size_t)p * NB + bq) * 128 + col] = v[r] + bv;
                    }
                }
            }
        }
    }
}

// ---------------------------------------------------------------------------
// FF block FUSED, MT=1: ff1 (256->1024) + GELU -> F1T[k][mrow] LDS (bf16x4
// vector writes) + ff2 (1024->256) via tr_b16 A-frag reads + residual + LN.
// 16 rows/block, 500 blocks. LDS 33 KB.
// ---------------------------------------------------------------------------
__global__ __launch_bounds__(256) void k_fffused(
    const __bf16* __restrict__ PA, const __bf16* __restrict__ PB1,
    const float* __restrict__ b1, const __bf16* __restrict__ PB2,
    const float* __restrict__ b2, float* __restrict__ h,
    __bf16* __restrict__ PAout,
    const float* __restrict__ gam, const float* __restrict__ bet)
{
    __shared__ __align__(16) __bf16 F1T[1024][16];   // 32 KB, [k][m-row]
    __shared__ float redS[4][16];
    __shared__ float redQ[4][16];
    int t = threadIdx.x, lane = t & 63, w = t >> 6;
    int mt = blockIdx.x;                  // one 16-row m-tile
    int g_ = lane >> 4, cl = lane & 15, rbase = g_ * 4;

    const bf16x8* A8 = (const bf16x8*)PA;
    const bf16x8* B81 = (const bf16x8*)PB1;
    const bf16x8* B82 = (const bf16x8*)PB2;

    // ---- Phase A: ff1, wave w covers cols [w*256, w*256+256) ----
    f32x4 acc1[16] = {};
    #pragma unroll 2
    for (int ks = 0; ks < 8; ks++) {
        bf16x8 a = A8[((size_t)mt * 8 + ks) * 64 + lane];
        #pragma unroll
        for (int n = 0; n < 16; n++) {
            bf16x8 b = B81[((size_t)(w * 16 + n) * 8 + ks) * 64 + lane];
            acc1[n] = __builtin_amdgcn_mfma_f32_16x16x32_bf16(a, b, acc1[n], 0, 0, 0);
        }
    }
    // GELU -> F1T[col][rbase..rbase+3] (C-frag rows contiguous -> bf16x4)
    #pragma unroll
    for (int n = 0; n < 16; n++) {
        int col = (w * 16 + n) * 16 + cl;
        float bv = b1[col];
        bf16x4 pv;
        #pragma unroll
        for (int r = 0; r < 4; r++) {
            float xx = acc1[n][r] + bv;
            pv[r] = (__bf16)(0.5f * xx * (1.0f + erff(xx * 0.70710678118654752f)));
        }
        *(bf16x4*)&F1T[col][rbase] = pv;
    }
    __syncthreads();

    // ---- Phase B: ff2, K=1024 (32 ks-tiles); A-frags via tr_b16 ----
    f32x4 acc[4] = {};
    for (int kb = 0; kb < 8; kb++) {
        f32x2 lo[4], hi[4];
        #pragma unroll
        for (int q = 0; q < 4; q++) {
            unsigned ta = (unsigned)(uintptr_t)&F1T[(kb * 4 + q) * 32 + 8 * g_][0] + cl * 8;
            asm volatile("ds_read_b64_tr_b16 %0, %1" : "=v"(lo[q]) : "v"(ta) : "memory");
            asm volatile("ds_read_b64_tr_b16 %0, %1 offset:128" : "=v"(hi[q]) : "v"(ta) : "memory");
        }
        asm volatile("s_waitcnt lgkmcnt(0)" ::: "memory");
        __builtin_amdgcn_sched_barrier(0);
        #pragma unroll
        for (int q = 0; q < 4; q++) {
            int ks = kb * 4 + q;
            f32x4 pc = {lo[q][0], lo[q][1], hi[q][0], hi[q][1]};
            bf16x8 a = __builtin_bit_cast(bf16x8, pc);
            #pragma unroll
            for (int n = 0; n < 4; n++) {
                bf16x8 b = B82[((size_t)(w * 4 + n) * 32 + ks) * 64 + lane];
                acc[n] = __builtin_amdgcn_mfma_f32_16x16x32_bf16(a, b, acc[n], 0, 0, 0);
            }
        }
    }

    // ---- EPI: +b2, residual -> h, LN -> PA ----
    float gamv[4], betv[4];
    #pragma unroll
    for (int n = 0; n < 4; n++) {
        int col = (w * 4 + n) * 16 + cl;
        float bv = b2[col];
        gamv[n] = gam[col]; betv[n] = bet[col];
        int row = mt * 16 + rbase;
        #pragma unroll
        for (int r = 0; r < 4; r++) {
            float v = acc[n][r] + bv + h[(size_t)(row + r) * 256 + col];
            h[(size_t)(row + r) * 256 + col] = v;
            acc[n][r] = v;
        }
    }
    float mu[4], rstd[4];
    {
        float ps[4];
        #pragma unroll
        for (int r = 0; r < 4; r++) {
            float s = acc[0][r] + acc[1][r] + acc[2][r] + acc[3][r];
            #pragma unroll
            for (int off = 1; off < 16; off <<= 1) s += __shfl_xor(s, off, 64);
            ps[r] = s;
        }
        if (cl == 0)
            #pragma unroll
            for (int r = 0; r < 4; r++) redS[w][rbase + r] = ps[r];
        __syncthreads();
        #pragma unroll
        for (int r = 0; r < 4; r++) {
            int lr = rbase + r;
            mu[r] = (redS[0][lr] + redS[1][lr] + redS[2][lr] + redS[3][lr]) * (1.0f / 256.0f);
        }
        float pq[4];
        #pragma unroll
        for (int r = 0; r < 4; r++) {
            float s = 0.f;
            #pragma unroll
            for (int n = 0; n < 4; n++) { float d = acc[n][r] - mu[r]; s += d * d; }
            #pragma unroll
            for (int off = 1; off < 16; off <<= 1) s += __shfl_xor(s, off, 64);
            pq[r] = s;
        }
        if (cl == 0)
            #pragma unroll
            for (int r = 0; r < 4; r++) redQ[w][rbase + r] = pq[r];
        __syncthreads();
        #pragma unroll
        for (int r = 0; r < 4; r++) {
            int lr = rbase + r;
            float var = (redQ[0][lr] + redQ[1][lr] + redQ[2][lr] + redQ[3][lr]) * (1.0f / 256.0f);
            rstd[r] = rsqrtf(var + 1e-5f);
        }
    }
    int row = mt * 16 + rbase;
    #pragma unroll
    for (int n = 0; n < 4; n++) {
        int col = (w * 4 + n) * 16 + cl;
        #pragma unroll
        for (int r = 0; r < 4; r++) {
            float y = (acc[n][r] - mu[r]) * rstd[r] * gamv[n] + betv[n];
            pa_store(PAout, 8, row + r, col, y);
        }
    }
}

// ---------------------------------------------------------------------------
// MFMA flash attention (unchanged from round 10).
// ---------------------------------------------------------------------------
__global__ __launch_bounds__(256) void k_attn(
    const __bf16* __restrict__ qkv, const float* __restrict__ rel_bias,
    __bf16* __restrict__ PA)
{
    __shared__ __align__(16) __bf16 Kfr[4][64][8];
    __shared__ __align__(16) __bf16 Vpl[2][64][16];
    __shared__ __align__(16) __bf16 PT[4][64][16];
    __shared__ float bias_s[132];

    int bh = blockIdx.x, qt = 7 - blockIdx.y;   // heavy tiles first
    int b = bh >> 3, hh = bh & 7;
    int q0 = qt * 64;
    int t = threadIdx.x, lane = t & 63, w = t >> 6;
    int c = lane & 15, g = lane >> 4;

    const __bf16* base = qkv + (size_t)b * TS * 768 + hh * 32;

    if (t < 129) bias_s[t] = rel_bias[hh * 129 + t];

    bf16x8 aq = {};
    {
        int qi = q0 + 16 * w + c;
        if (qi < TS) aq = *(const bf16x8*)(base + (size_t)qi * 768 + 8 * g);
    }

    float lpart[4] = {0.f, 0.f, 0.f, 0.f};
    f32x4 O0 = {}, O1 = {};
    const float scale = 0.17677669529663687f;

    int nj = qt + 1;

    for (int it = 0; it < nj; it++) {
        int j0 = it * 64;
        __syncthreads();
        {
            int j = j0 + w * 16 + c;
            bf16x8 kv = {};
            if (j < TS) kv = *(const bf16x8*)(base + (size_t)j * 768 + 256 + 8 * g);
            *(bf16x8*)&Kfr[w][lane][0] = kv;
        }
        {
            int jl = t >> 2, dseg = t & 3;
            int j = j0 + jl;
            bf16x8 vv = {};
            if (j < TS) vv = *(const bf16x8*)(base + (size_t)j * 768 + 512 + 8 * dseg);
            *(bf16x8*)&Vpl[dseg >> 1][jl][(dseg & 1) * 8] = vv;
        }
        __syncthreads();

        f32x4 S[4];
        f32x4 zero = {};
        #pragma unroll
        for (int jt = 0; jt < 4; jt++) {
            bf16x8 bk = *(const bf16x8*)&Kfr[jt][lane][0];
            S[jt] = __builtin_amdgcn_mfma_f32_16x16x32_bf16(aq, bk, zero, 0, 0, 0);
        }

        #pragma unroll
        for (int jt = 0; jt < 4; jt++) {
            int j = j0 + jt * 16 + c;
            #pragma unroll
            for (int r = 0; r < 4; r++) {
                int i = q0 + 16 * w + 4 * g + r;
                int rel = j - i;
                rel = rel < -64 ? -64 : (rel > 64 ? 64 : rel);
                float sv = S[jt][r] * scale + bias_s[rel + 64];
                float p = (j > i) ? 0.f : __expf(sv);
                S[jt][r] = p;
                lpart[r] += p;
            }
        }

        #pragma unroll
        for (int jt = 0; jt < 4; jt++) {
            bf16x4 pv;
            pv[0] = (__bf16)S[jt][0]; pv[1] = (__bf16)S[jt][1];
            pv[2] = (__bf16)S[jt][2]; pv[3] = (__bf16)S[jt][3];
            *(bf16x4*)&PT[w][jt * 16 + c][4 * g] = pv;
        }
        asm volatile("s_waitcnt lgkmcnt(0)" ::: "memory");
        __builtin_amdgcn_sched_barrier(0);

        f32x2 pa_lo[2], pa_hi[2], vb_lo[2][2], vb_hi[2][2];
        #pragma unroll
        for (int jb = 0; jb < 2; jb++) {
            unsigned pta = (unsigned)(uintptr_t)&PT[w][jb * 32 + 8 * g][0] + c * 8;
            asm volatile("ds_read_b64_tr_b16 %0, %1" : "=v"(pa_lo[jb]) : "v"(pta) : "memory");
            asm volatile("ds_read_b64_tr_b16 %0, %1 offset:128" : "=v"(pa_hi[jb]) : "v"(pta) : "memory");
            #pragma unroll
            for (int dh = 0; dh < 2; dh++) {
                unsigned vta = (unsigned)(uintptr_t)&Vpl[dh][jb * 32 + 8 * g][0] + c * 8;
                asm volatile("ds_read_b64_tr_b16 %0, %1" : "=v"(vb_lo[jb][dh]) : "v"(vta) : "memory");
                asm volatile("ds_read_b64_tr_b16 %0, %1 offset:128" : "=v"(vb_hi[jb][dh]) : "v"(vta) : "memory");
            }
        }
        asm volatile("s_waitcnt lgkmcnt(0)" ::: "memory");
        __builtin_amdgcn_sched_barrier(0);

        #pragma unroll
        for (int jb = 0; jb < 2; jb++) {
            f32x4 pc = {pa_lo[jb][0], pa_lo[jb][1], pa_hi[jb][0], pa_hi[jb][1]};
            bf16x8 pa = __builtin_bit_cast(bf16x8, pc);
            f32x4 v0c = {vb_lo[jb][0][0], vb_lo[jb][0][1], vb_hi[jb][0][0], vb_hi[jb][0][1]};
            f32x4 v1c = {vb_lo[jb][1][0], vb_lo[jb][1][1], vb_hi[jb][1][0], vb_hi[jb][1][1]};
            bf16x8 vb0 = __builtin_bit_cast(bf16x8, v0c);
            bf16x8 vb1 = __builtin_bit_cast(bf16x8, v1c);
            O0 = __builtin_amdgcn_mfma_f32_16x16x32_bf16(pa, vb0, O0, 0, 0, 0);
            O1 = __builtin_amdgcn_mfma_f32_16x16x32_bf16(pa, vb1, O1, 0, 0, 0);
        }
    }

    #pragma unroll
    for (int r = 0; r < 4; r++) {
        #pragma unroll
        for (int off = 1; off < 16; off <<= 1) lpart[r] += __shfl_xor(lpart[r], off, 64);
    }
    #pragma unroll
    for (int r = 0; r < 4; r++) {
        int i = q0 + 16 * w + 4 * g + r;
        if (i < TS) {
            float inv = 1.0f / lpart[r];
            int grow = b * TS + i;
            int mt = grow >> 4, rl = grow & 15;
            size_t fb = (size_t)(mt * 8 + hh) * 64;
            PA[(fb + ((c >> 3) & 1) * 16 + rl) * 8 + (c & 7)]       = (__bf16)(O0[r] * inv);
            PA[(fb + (2 + ((c >> 3) & 1)) * 16 + rl) * 8 + (c & 7)] = (__bf16)(O1[r] * inv);
        }
    }
}

extern "C" void kernel_launch(void* const* d_in, const int* in_sizes, int n_in,
                              void* d_out, int out_size, void* d_ws, size_t ws_size,
                              hipStream_t stream)
{
    const float* x        = (const float*)d_in[0];
    const float* ln1_g    = (const float*)d_in[1];
    const float* ln1_b    = (const float*)d_in[2];
    const float* proj_w   = (const float*)d_in[3];
    const float* proj_b   = (const float*)d_in[4];
    const float* ln2_g    = (const float*)d_in[5];
    const float* ln2_b    = (const float*)d_in[6];
    const float* rel_bias = (const float*)d_in[7];
    const float* ln_attn_g= (const float*)d_in[8];
    const float* ln_attn_b= (const float*)d_in[9];
    const float* qkv_w    = (const float*)d_in[10];
    const float* qkv_b    = (const float*)d_in[11];
    const float* out_w    = (const float*)d_in[12];
    const float* out_b    = (const float*)d_in[13];
    const float* ln_ff_g  = (const float*)d_in[14];
    const float* ln_ff_b  = (const float*)d_in[15];
    const float* ff1_w    = (const float*)d_in[16];
    const float* ff1_b    = (const float*)d_in[17];
    const float* ff2_w    = (const float*)d_in[18];
    const float* ff2_b    = (const float*)d_in[19];
    const float* fln_g    = (const float*)d_in[20];
    const float* fln_b    = (const float*)d_in[21];
    const float* op_w     = (const float*)d_in[22];
    const float* op_b     = (const float*)d_in[23];
    float* out = (float*)d_out;

    char* ws = (char*)d_ws;
    float*  h     = (float*)(ws);                      //  8,192,000 B
    __bf16* qkvb  = (__bf16*)(ws + 8192000);           // 12,288,000 B
    __bf16* PA    = (__bf16*)(ws + 20480000);          //  4,096,000 B
    __bf16* PBq   = (__bf16*)(ws + 24576000);          //  1,572,864 B
    __bf16* PBo   = (__bf16*)(ws + 26148864);          //    524,288 B
    __bf16* PB1   = (__bf16*)(ws + 26673152);          //  2,097,152 B
    __bf16* PB2   = (__bf16*)(ws + 28770304);          //  2,097,152 B
    __bf16* PBp   = (__bf16*)(ws + 30867456);          //    262,144 B
    __bf16* PBop  = (__bf16*)(ws + 31129600);          //     65,536 B

    // ---- all weight packs, one kernel ----
    k_pack_all<<<1616, 256, 0, stream>>>(qkv_w, out_w, ff1_w, ff2_w, proj_w, op_w,
                                         PBq, PBo, PB1, PB2, PBp, PBop);

    // ---- patch fused: gather+LN1 -> LDS -> GEMM -> LN2 -> h, LN_attn0 -> PA ----
    k_patchfused<<<250, 256, 0, stream>>>(x, ln1_g, ln1_b, PBp, proj_b, h, PA,
                                          ln2_g, ln2_b, ln_attn_g, ln_attn_b);

    for (int l = 0; l < 4; l++) {
        k_gemm<8, 2, 4, 0><<<dim3(250, 3), 256, 0, stream>>>(PA, PBq + (size_t)l * 196608,
                                                             qkv_b + l * 768, nullptr, qkvb,
                                                             nullptr, nullptr);
        dim3 ag(NB * NHEAD, 8);
        k_attn<<<ag, 256, 0, stream>>>(qkvb, rel_bias, PA);
        // out-proj + residual -> h, LN_ff -> PA (MT=1, 500 blocks)
        k_gemm<8, 1, 4, 4><<<dim3(500, 1), 256, 0, stream>>>(PA, PBo + (size_t)l * 65536,
                                                             out_b + l * 256, h, PA,
                                                             ln_ff_g + l * 256, ln_ff_b + l * 256);
        // ff1+GELU+ff2 fused (MT=1, 500 blocks) + residual -> h, next LN -> PA
        const float* ng = (l < 3) ? (ln_attn_g + (l + 1) * 256) : fln_g;
        const float* nb = (l < 3) ? (ln_attn_b + (l + 1) * 256) : fln_b;
        k_fffused<<<500, 256, 0, stream>>>(PA, PB1 + (size_t)l * 262144, ff1_b + l * 1024,
                                           PB2 + (size_t)l * 262144, ff2_b + l * 256,
                                           h, PA, ng, nb);
    }
    // final projection: PA(fln-normalized) x op_w -> swapaxes fp32 out (MT=1)
    k_gemm<8, 1, 2, 5><<<dim3(500, 1), 256, 0, stream>>>(PA, PBop, op_b, out, nullptr,
                                                         nullptr, nullptr);
}

// Round 13
// 346.846 us; speedup vs baseline: 1.0220x; 1.0220x over previous
//
#include <hip/hip_runtime.h>

#define TS 500      // n_patch (sequence length)
#define NB 16       // batch
#define NROW 8000   // NB * TS
#define DMODEL 256
#define NHEAD 8
#define HDIM 32
#define FFD 1024

typedef __bf16 bf16x8 __attribute__((ext_vector_type(8)));
typedef __bf16 bf16x4 __attribute__((ext_vector_type(4)));
typedef float  f32x4  __attribute__((ext_vector_type(4)));
typedef float  f32x2  __attribute__((ext_vector_type(2)));

__device__ __forceinline__ float wred_sum(float v) {
    #pragma unroll
    for (int off = 32; off; off >>= 1) v += __shfl_xor(v, off, 64);
    return v;
}

// A-fragment scatter store (global): element (grow, col) of [8000][K] bf16,
// KS = K/32 fragments per row-tile.
__device__ __forceinline__ void pa_store(__bf16* __restrict__ PA, int KS,
                                         int grow, int col, float y) {
    int mt = grow >> 4, rl = grow & 15;
    size_t idx = ((size_t)(mt * KS + (col >> 5)) * 64 + ((col >> 3) & 3) * 16 + rl) * 8 + (col & 7);
    PA[idx] = (__bf16)y;
}

// A-fragment scatter store (LDS, local row 0..R*16-1, KS=8)
__device__ __forceinline__ void ya_store(__bf16* __restrict__ YA,
                                         int lrow, int col, float y) {
    int mtl = lrow >> 4, rl = lrow & 15;
    int idx = (((mtl * 8 + (col >> 5)) * 64) + ((col >> 3) & 3) * 16 + rl) * 8 + (col & 7);
    YA[idx] = (__bf16)y;
}

// ---------------------------------------------------------------------------
// All weight packs in ONE kernel. Flat grid of 1616 blocks, range dispatch.
// ---------------------------------------------------------------------------
__global__ __launch_bounds__(256) void k_pack_all(
    const float* __restrict__ qkv_w, const float* __restrict__ out_w,
    const float* __restrict__ ff1_w, const float* __restrict__ ff2_w,
    const float* __restrict__ proj_w, const float* __restrict__ op_w,
    __bf16* __restrict__ PBq, __bf16* __restrict__ PBo,
    __bf16* __restrict__ PB1, __bf16* __restrict__ PB2,
    __bf16* __restrict__ PBp, __bf16* __restrict__ PBop)
{
    int bid = blockIdx.x;
    const float* W; __bf16* PB; int KS, NT, wLS, pLS, l, bx;
    if (bid < 384)       { W = qkv_w;  PB = PBq;  KS = 8;  NT = 48; wLS = 196608; pLS = 196608; l = bid / 96;           bx = bid % 96; }
    else if (bid < 512)  { W = out_w;  PB = PBo;  KS = 8;  NT = 16; wLS = 65536;  pLS = 65536;  l = (bid - 384) / 32;   bx = (bid - 384) % 32; }
    else if (bid < 1024) { W = ff1_w;  PB = PB1;  KS = 8;  NT = 64; wLS = 262144; pLS = 262144; l = (bid - 512) / 128;  bx = (bid - 512) % 128; }
    else if (bid < 1536) { W = ff2_w;  PB = PB2;  KS = 32; NT = 16; wLS = 262144; pLS = 262144; l = (bid - 1024) / 128; bx = (bid - 1024) % 128; }
    else if (bid < 1600) { W = proj_w; PB = PBp;  KS = 16; NT = 16; wLS = 0;      pLS = 0;      l = 0;                  bx = bid - 1536; }
    else                 { W = op_w;   PB = PBop; KS = 8;  NT = 8;  wLS = 0;      pLS = 0;      l = 0;                  bx = bid - 1600; }

    int gid = bx * 256 + threadIdx.x;
    if (gid >= NT * KS * 64) return;
    int lane = gid & 63;
    int ks = (gid >> 6) % KS;
    int nt = (gid >> 6) / KS;
    int N = NT * 16;
    int k0 = ks * 32 + (lane >> 4) * 8;
    int col = nt * 16 + (lane & 15);
    const float* src = W + (size_t)l * wLS;
    bf16x8 v;
    #pragma unroll
    for (int j = 0; j < 8; j++) v[j] = (__bf16)src[(size_t)(k0 + j) * N + col];
    *(bf16x8*)(PB + (size_t)l * pLS + ((size_t)(nt * KS + ks) * 64 + lane) * 8) = v;
}

// ---------------------------------------------------------------------------
// Patch stage FUSED + qkv[0]: gather 4x128->512, LN1, A-frags to LDS, MFMA
// 512->256, +bias+LN2 -> h, LN_attn0 -> LDS A-frags, qkv GEMM -> qkvb.
// 32 rows/block, 250 blocks.
// ---------------------------------------------------------------------------
__global__ __launch_bounds__(256) void k_patchfused(
    const float* __restrict__ x, const float* __restrict__ g1, const float* __restrict__ b1,
    const __bf16* __restrict__ PBp, const float* __restrict__ bias,
    float* __restrict__ h,
    const float* __restrict__ gam, const float* __restrict__ bet,
    const float* __restrict__ gam2, const float* __restrict__ bet2,
    const __bf16* __restrict__ PBq0, const float* __restrict__ qb0,
    __bf16* __restrict__ qkvb)
{
    __shared__ __align__(16) __bf16 As[2][16][64][8];   // 32 KB; reused as YA
    __shared__ float redS[4][32];
    __shared__ float redQ[4][32];
    int t = threadIdx.x, lane = t & 63, w = t >> 6;
    int row0 = blockIdx.x * 32;

    for (int rr = 0; rr < 8; rr++) {
        int lrow = w * 8 + rr;
        int row = row0 + lrow;
        int b = row / TS, pp = row - b * TS;
        int kb = lane * 8;
        const float* src = x + ((size_t)(pp * 4 + (kb >> 7)) * NB + b) * 128 + (kb & 127);
        float4 lo = *(const float4*)src;
        float4 hi = *(const float4*)(src + 4);
        float v[8] = {lo.x, lo.y, lo.z, lo.w, hi.x, hi.y, hi.z, hi.w};
        float sm_ = 0.f;
        #pragma unroll
        for (int j = 0; j < 8; j++) sm_ += v[j];
        sm_ = wred_sum(sm_);
        float mu = sm_ * (1.0f / 512.0f);
        float q = 0.f;
        #pragma unroll
        for (int j = 0; j < 8; j++) { float d = v[j] - mu; q += d * d; }
        q = wred_sum(q);
        float rs = rsqrtf(q * (1.0f / 512.0f) + 1e-6f);
        float4 gl = *(const float4*)(g1 + kb), gh = *(const float4*)(g1 + kb + 4);
        float4 bl = *(const float4*)(b1 + kb), bh = *(const float4*)(b1 + kb + 4);
        float gg[8] = {gl.x, gl.y, gl.z, gl.w, gh.x, gh.y, gh.z, gh.w};
        float bbv[8] = {bl.x, bl.y, bl.z, bl.w, bh.x, bh.y, bh.z, bh.w};
        bf16x8 yv;
        #pragma unroll
        for (int j = 0; j < 8; j++) yv[j] = (__bf16)((v[j] - mu) * rs * gg[j] + bbv[j]);
        *(bf16x8*)&As[lrow >> 4][lane >> 2][(lane & 3) * 16 + (lrow & 15)][0] = yv;
    }
    __syncthreads();

    const bf16x8* B8 = (const bf16x8*)PBp;
    f32x4 acc[2][4] = {};
    #pragma unroll 8
    for (int ks = 0; ks < 16; ks++) {
        bf16x8 a0 = *(const bf16x8*)&As[0][ks][lane][0];
        bf16x8 a1 = *(const bf16x8*)&As[1][ks][lane][0];
        #pragma unroll
        for (int n = 0; n < 4; n++) {
            bf16x8 b = B8[((size_t)(w * 4 + n) * 16 + ks) * 64 + lane];
            acc[0][n] = __builtin_amdgcn_mfma_f32_16x16x32_bf16(a0, b, acc[0][n], 0, 0, 0);
            acc[1][n] = __builtin_amdgcn_mfma_f32_16x16x32_bf16(a1, b, acc[1][n], 0, 0, 0);
        }
    }

    int g_ = lane >> 4, cl = lane & 15;
    int rbase = g_ * 4;
    float gamv[4], betv[4], gam2v[4], bet2v[4];
    #pragma unroll
    for (int n = 0; n < 4; n++) {
        int col = (w * 4 + n) * 16 + cl;
        float bv = bias[col];
        gamv[n] = gam[col]; betv[n] = bet[col];
        gam2v[n] = gam2[col]; bet2v[n] = bet2[col];
        #pragma unroll
        for (int m = 0; m < 2; m++)
            #pragma unroll
            for (int r = 0; r < 4; r++) acc[m][n][r] += bv;
    }
    float mu[2][4], rstd[2][4];
    {
        float ps[2][4];
        #pragma unroll
        for (int m = 0; m < 2; m++)
            #pragma unroll
            for (int r = 0; r < 4; r++) {
                float s2 = acc[m][0][r] + acc[m][1][r] + acc[m][2][r] + acc[m][3][r];
                #pragma unroll
                for (int off = 1; off < 16; off <<= 1) s2 += __shfl_xor(s2, off, 64);
                ps[m][r] = s2;
            }
        if (cl == 0)
            #pragma unroll
            for (int m = 0; m < 2; m++)
                #pragma unroll
                for (int r = 0; r < 4; r++) redS[w][m * 16 + rbase + r] = ps[m][r];
        __syncthreads();
        #pragma unroll
        for (int m = 0; m < 2; m++)
            #pragma unroll
            for (int r = 0; r < 4; r++) {
                int lr = m * 16 + rbase + r;
                mu[m][r] = (redS[0][lr] + redS[1][lr] + redS[2][lr] + redS[3][lr]) * (1.0f / 256.0f);
            }
        float pq[2][4];
        #pragma unroll
        for (int m = 0; m < 2; m++)
            #pragma unroll
            for (int r = 0; r < 4; r++) {
                float s2 = 0.f;
                #pragma unroll
                for (int n = 0; n < 4; n++) { float d = acc[m][n][r] - mu[m][r]; s2 += d * d; }
                #pragma unroll
                for (int off = 1; off < 16; off <<= 1) s2 += __shfl_xor(s2, off, 64);
                pq[m][r] = s2;
            }
        if (cl == 0)
            #pragma unroll
            for (int m = 0; m < 2; m++)
                #pragma unroll
                for (int r = 0; r < 4; r++) redQ[w][m * 16 + rbase + r] = pq[m][r];
        __syncthreads();
        #pragma unroll
        for (int m = 0; m < 2; m++)
            #pragma unroll
            for (int r = 0; r < 4; r++) {
                int lr = m * 16 + rbase + r;
                float var = (redQ[0][lr] + redQ[1][lr] + redQ[2][lr] + redQ[3][lr]) * (1.0f / 256.0f);
                rstd[m][r] = rsqrtf(var + 1e-6f);
            }
    }
    // y1 = LN2(acc) -> h; second LN stats
    float ps2[2][4];
    #pragma unroll
    for (int m = 0; m < 2; m++) {
        int row = row0 + m * 16 + rbase;
        #pragma unroll
        for (int r = 0; r < 4; r++) {
            float s2 = 0.f;
            #pragma unroll
            for (int n = 0; n < 4; n++) {
                int col = (w * 4 + n) * 16 + cl;
                float y1 = (acc[m][n][r] - mu[m][r]) * rstd[m][r] * gamv[n] + betv[n];
                h[(size_t)(row + r) * 256 + col] = y1;
                s2 += y1;
            }
            #pragma unroll
            for (int off = 1; off < 16; off <<= 1) s2 += __shfl_xor(s2, off, 64);
            ps2[m][r] = s2;
        }
    }
    if (cl == 0)
        #pragma unroll
        for (int m = 0; m < 2; m++)
            #pragma unroll
            for (int r = 0; r < 4; r++) redS[w][m * 16 + rbase + r] = ps2[m][r];
    __syncthreads();
    float mu2[2][4], rstd2[2][4];
    #pragma unroll
    for (int m = 0; m < 2; m++)
        #pragma unroll
        for (int r = 0; r < 4; r++) {
            int lr = m * 16 + rbase + r;
            mu2[m][r] = (redS[0][lr] + redS[1][lr] + redS[2][lr] + redS[3][lr]) * (1.0f / 256.0f);
        }
    float pq2[2][4];
    #pragma unroll
    for (int m = 0; m < 2; m++)
        #pragma unroll
        for (int r = 0; r < 4; r++) {
            float s2 = 0.f;
            #pragma unroll
            for (int n = 0; n < 4; n++) {
                float y1 = (acc[m][n][r] - mu[m][r]) * rstd[m][r] * gamv[n] + betv[n];
                float d = y1 - mu2[m][r];
                s2 += d * d;
            }
            #pragma unroll
            for (int off = 1; off < 16; off <<= 1) s2 += __shfl_xor(s2, off, 64);
            pq2[m][r] = s2;
        }
    if (cl == 0)
        #pragma unroll
        for (int m = 0; m < 2; m++)
            #pragma unroll
            for (int r = 0; r < 4; r++) redQ[w][m * 16 + rbase + r] = pq2[m][r];
    __syncthreads();
    #pragma unroll
    for (int m = 0; m < 2; m++)
        #pragma unroll
        for (int r = 0; r < 4; r++) {
            int lr = m * 16 + rbase + r;
            float var = (redQ[0][lr] + redQ[1][lr] + redQ[2][lr] + redQ[3][lr]) * (1.0f / 256.0f);
            rstd2[m][r] = rsqrtf(var + 1e-5f);
        }
    // y2 = LN_attn0(y1) -> LDS A-frags (reuse As; all waves past GEMM reads
    // due to the LN syncthreads above)
    __bf16* YA = &As[0][0][0][0];   // [2][8][64][8]
    #pragma unroll
    for (int m = 0; m < 2; m++) {
        #pragma unroll
        for (int n = 0; n < 4; n++) {
            int col = (w * 4 + n) * 16 + cl;
            #pragma unroll
            for (int r = 0; r < 4; r++) {
                float y1 = (acc[m][n][r] - mu[m][r]) * rstd[m][r] * gamv[n] + betv[n];
                float y2 = (y1 - mu2[m][r]) * rstd2[m][r] * gam2v[n] + bet2v[n];
                ya_store(YA, m * 16 + rbase + r, col, y2);
            }
        }
    }
    __syncthreads();

    // qkv GEMM for layer 0: K=256 (KS=8), 48 n-tiles, wave w owns 12.
    const bf16x8* YA8 = (const bf16x8*)YA;
    const bf16x8* B8q = (const bf16x8*)PBq0;
    for (int m = 0; m < 2; m++) {
        f32x4 acc2[12] = {};
        for (int ks = 0; ks < 8; ks++) {
            bf16x8 a = YA8[(m * 8 + ks) * 64 + lane];
            #pragma unroll
            for (int n = 0; n < 12; n++) {
                bf16x8 b = B8q[((size_t)(w * 12 + n) * 8 + ks) * 64 + lane];
                acc2[n] = __builtin_amdgcn_mfma_f32_16x16x32_bf16(a, b, acc2[n], 0, 0, 0);
            }
        }
        int row = row0 + m * 16 + rbase;
        #pragma unroll
        for (int n = 0; n < 12; n++) {
            int col = (w * 12 + n) * 16 + cl;
            float bv = qb0[col];
            #pragma unroll
            for (int r = 0; r < 4; r++)
                qkvb[(size_t)(row + r) * 768 + col] = (__bf16)(acc2[n][r] + bv);
        }
    }
}

// ---------------------------------------------------------------------------
// Out-projection GEMM (EPI4): h += acc+bias; LN(h) -> PA. MT=1, 500 blocks.
// ---------------------------------------------------------------------------
__global__ __launch_bounds__(256) void k_outproj(
    const __bf16* __restrict__ PA, const __bf16* __restrict__ PB,
    const float* __restrict__ bias, float* __restrict__ dst,
    __bf16* __restrict__ dstb,
    const float* __restrict__ gam, const float* __restrict__ bet)
{
    __shared__ float redS[4][16];
    __shared__ float redQ[4][16];
    int t = threadIdx.x, lane = t & 63, w = t >> 6;
    int mt0 = blockIdx.x;

    const bf16x8* A8 = (const bf16x8*)PA;
    const bf16x8* B8 = (const bf16x8*)PB;

    f32x4 acc[4] = {};
    #pragma unroll 8
    for (int ks = 0; ks < 8; ks++) {
        bf16x8 a = A8[((size_t)mt0 * 8 + ks) * 64 + lane];
        #pragma unroll
        for (int n = 0; n < 4; n++) {
            bf16x8 b = B8[((size_t)(w * 4 + n) * 8 + ks) * 64 + lane];
            acc[n] = __builtin_amdgcn_mfma_f32_16x16x32_bf16(a, b, acc[n], 0, 0, 0);
        }
    }

    int g_ = lane >> 4, cl = lane & 15;
    int rbase = g_ * 4;
    float gamv[4], betv[4];
    #pragma unroll
    for (int n = 0; n < 4; n++) {
        int col = (w * 4 + n) * 16 + cl;
        float bv = bias[col];
        gamv[n] = gam[col]; betv[n] = bet[col];
        int row = mt0 * 16 + rbase;
        #pragma unroll
        for (int r = 0; r < 4; r++) {
            float v = acc[n][r] + bv + dst[(size_t)(row + r) * 256 + col];
            dst[(size_t)(row + r) * 256 + col] = v;
            acc[n][r] = v;
        }
    }
    float mu[4], rstd[4];
    {
        float ps[4];
        #pragma unroll
        for (int r = 0; r < 4; r++) {
            float s2 = acc[0][r] + acc[1][r] + acc[2][r] + acc[3][r];
            #pragma unroll
            for (int off = 1; off < 16; off <<= 1) s2 += __shfl_xor(s2, off, 64);
            ps[r] = s2;
        }
        if (cl == 0)
            #pragma unroll
            for (int r = 0; r < 4; r++) redS[w][rbase + r] = ps[r];
        __syncthreads();
        #pragma unroll
        for (int r = 0; r < 4; r++) {
            int lr = rbase + r;
            mu[r] = (redS[0][lr] + redS[1][lr] + redS[2][lr] + redS[3][lr]) * (1.0f / 256.0f);
        }
        float pq[4];
        #pragma unroll
        for (int r = 0; r < 4; r++) {
            float s2 = 0.f;
            #pragma unroll
            for (int n = 0; n < 4; n++) { float d = acc[n][r] - mu[r]; s2 += d * d; }
            #pragma unroll
            for (int off = 1; off < 16; off <<= 1) s2 += __shfl_xor(s2, off, 64);
            pq[r] = s2;
        }
        if (cl == 0)
            #pragma unroll
            for (int r = 0; r < 4; r++) redQ[w][rbase + r] = pq[r];
        __syncthreads();
        #pragma unroll
        for (int r = 0; r < 4; r++) {
            int lr = rbase + r;
            float var = (redQ[0][lr] + redQ[1][lr] + redQ[2][lr] + redQ[3][lr]) * (1.0f / 256.0f);
            rstd[r] = rsqrtf(var + 1e-5f);
        }
    }
    int row = mt0 * 16 + rbase;
    #pragma unroll
    for (int n = 0; n < 4; n++) {
        int col = (w * 4 + n) * 16 + cl;
        #pragma unroll
        for (int r = 0; r < 4; r++) {
            float y = (acc[n][r] - mu[r]) * rstd[r] * gamv[n] + betv[n];
            pa_store(dstb, 8, row + r, col, y);
        }
    }
}

// ---------------------------------------------------------------------------
// FF block FUSED + next GEMM. MODE 0: tail = qkv[l+1] (256->768) -> qkvb.
// MODE 1: tail = final projection (256->128) -> out (swapaxes).
// 16 rows/block, 500 blocks. LDS 33 KB (F1T reused for YA).
// ---------------------------------------------------------------------------
template<int MODE>
__global__ __launch_bounds__(256) void k_fffused(
    const __bf16* __restrict__ PA, const __bf16* __restrict__ PB1,
    const float* __restrict__ b1, const __bf16* __restrict__ PB2,
    const float* __restrict__ b2, float* __restrict__ h,
    const float* __restrict__ gam, const float* __restrict__ bet,
    const __bf16* __restrict__ PBn, const float* __restrict__ bn,
    __bf16* __restrict__ qkvb, float* __restrict__ outp)
{
    __shared__ __align__(16) __bf16 F1T[1024][16];   // 32 KB; head reused as YA
    __shared__ float redS[4][16];
    __shared__ float redQ[4][16];
    int t = threadIdx.x, lane = t & 63, w = t >> 6;
    int mt = blockIdx.x;
    int g_ = lane >> 4, cl = lane & 15, rbase = g_ * 4;

    const bf16x8* A8 = (const bf16x8*)PA;
    const bf16x8* B81 = (const bf16x8*)PB1;
    const bf16x8* B82 = (const bf16x8*)PB2;

    // ---- Phase A: ff1, wave w covers cols [w*256, w*256+256) ----
    f32x4 acc1[16] = {};
    #pragma unroll 2
    for (int ks = 0; ks < 8; ks++) {
        bf16x8 a = A8[((size_t)mt * 8 + ks) * 64 + lane];
        #pragma unroll
        for (int n = 0; n < 16; n++) {
            bf16x8 b = B81[((size_t)(w * 16 + n) * 8 + ks) * 64 + lane];
            acc1[n] = __builtin_amdgcn_mfma_f32_16x16x32_bf16(a, b, acc1[n], 0, 0, 0);
        }
    }
    #pragma unroll
    for (int n = 0; n < 16; n++) {
        int col = (w * 16 + n) * 16 + cl;
        float bv = b1[col];
        bf16x4 pv;
        #pragma unroll
        for (int r = 0; r < 4; r++) {
            float xx = acc1[n][r] + bv;
            pv[r] = (__bf16)(0.5f * xx * (1.0f + erff(xx * 0.70710678118654752f)));
        }
        *(bf16x4*)&F1T[col][rbase] = pv;
    }
    __syncthreads();

    // ---- Phase B: ff2, K=1024; A-frags via tr_b16 ----
    f32x4 acc[4] = {};
    for (int kb = 0; kb < 8; kb++) {
        f32x2 lo[4], hi[4];
        #pragma unroll
        for (int q = 0; q < 4; q++) {
            unsigned ta = (unsigned)(uintptr_t)&F1T[(kb * 4 + q) * 32 + 8 * g_][0] + cl * 8;
            asm volatile("ds_read_b64_tr_b16 %0, %1" : "=v"(lo[q]) : "v"(ta) : "memory");
            asm volatile("ds_read_b64_tr_b16 %0, %1 offset:128" : "=v"(hi[q]) : "v"(ta) : "memory");
        }
        asm volatile("s_waitcnt lgkmcnt(0)" ::: "memory");
        __builtin_amdgcn_sched_barrier(0);
        #pragma unroll
        for (int q = 0; q < 4; q++) {
            int ks = kb * 4 + q;
            f32x4 pc = {lo[q][0], lo[q][1], hi[q][0], hi[q][1]};
            bf16x8 a = __builtin_bit_cast(bf16x8, pc);
            #pragma unroll
            for (int n = 0; n < 4; n++) {
                bf16x8 b = B82[((size_t)(w * 4 + n) * 32 + ks) * 64 + lane];
                acc[n] = __builtin_amdgcn_mfma_f32_16x16x32_bf16(a, b, acc[n], 0, 0, 0);
            }
        }
    }

    // ---- EPI: +b2, residual -> h, LN -> YA (LDS) ----
    float gamv[4], betv[4];
    #pragma unroll
    for (int n = 0; n < 4; n++) {
        int col = (w * 4 + n) * 16 + cl;
        float bv = b2[col];
        gamv[n] = gam[col]; betv[n] = bet[col];
        int row = mt * 16 + rbase;
        #pragma unroll
        for (int r = 0; r < 4; r++) {
            float v = acc[n][r] + bv + h[(size_t)(row + r) * 256 + col];
            h[(size_t)(row + r) * 256 + col] = v;
            acc[n][r] = v;
        }
    }
    float mu[4], rstd[4];
    {
        float ps[4];
        #pragma unroll
        for (int r = 0; r < 4; r++) {
            float s2 = acc[0][r] + acc[1][r] + acc[2][r] + acc[3][r];
            #pragma unroll
            for (int off = 1; off < 16; off <<= 1) s2 += __shfl_xor(s2, off, 64);
            ps[r] = s2;
        }
        if (cl == 0)
            #pragma unroll
            for (int r = 0; r < 4; r++) redS[w][rbase + r] = ps[r];
        __syncthreads();
        #pragma unroll
        for (int r = 0; r < 4; r++) {
            int lr = rbase + r;
            mu[r] = (redS[0][lr] + redS[1][lr] + redS[2][lr] + redS[3][lr]) * (1.0f / 256.0f);
        }
        float pq[4];
        #pragma unroll
        for (int r = 0; r < 4; r++) {
            float s2 = 0.f;
            #pragma unroll
            for (int n = 0; n < 4; n++) { float d = acc[n][r] - mu[r]; s2 += d * d; }
            #pragma unroll
            for (int off = 1; off < 16; off <<= 1) s2 += __shfl_xor(s2, off, 64);
            pq[r] = s2;
        }
        if (cl == 0)
            #pragma unroll
            for (int r = 0; r < 4; r++) redQ[w][rbase + r] = pq[r];
        __syncthreads();   // also guarantees all waves done reading F1T
        #pragma unroll
        for (int r = 0; r < 4; r++) {
            int lr = rbase + r;
            float var = (redQ[0][lr] + redQ[1][lr] + redQ[2][lr] + redQ[3][lr]) * (1.0f / 256.0f);
            rstd[r] = rsqrtf(var + 1e-5f);
        }
    }
    // y -> LDS A-frags (reuse F1T head: [8][64][8] = 8 KB)
    __bf16* YA = &F1T[0][0];
    #pragma unroll
    for (int n = 0; n < 4; n++) {
        int col = (w * 4 + n) * 16 + cl;
        #pragma unroll
        for (int r = 0; r < 4; r++) {
            float y = (acc[n][r] - mu[r]) * rstd[r] * gamv[n] + betv[n];
            ya_store(YA, rbase + r, col, y);
        }
    }
    __syncthreads();

    // ---- tail GEMM from YA ----
    const bf16x8* YA8 = (const bf16x8*)YA;
    const bf16x8* B8n = (const bf16x8*)PBn;
    if constexpr (MODE == 0) {
        // qkv[l+1]: 48 n-tiles, wave owns 12
        f32x4 acc2[12] = {};
        for (int ks = 0; ks < 8; ks++) {
            bf16x8 a = YA8[ks * 64 + lane];
            #pragma unroll
            for (int n = 0; n < 12; n++) {
                bf16x8 b = B8n[((size_t)(w * 12 + n) * 8 + ks) * 64 + lane];
                acc2[n] = __builtin_amdgcn_mfma_f32_16x16x32_bf16(a, b, acc2[n], 0, 0, 0);
            }
        }
        int row = mt * 16 + rbase;
        #pragma unroll
        for (int n = 0; n < 12; n++) {
            int col = (w * 12 + n) * 16 + cl;
            float bv = bn[col];
            #pragma unroll
            for (int r = 0; r < 4; r++)
                qkvb[(size_t)(row + r) * 768 + col] = (__bf16)(acc2[n][r] + bv);
        }
    } else {
        // final projection: 8 n-tiles, wave owns 2; swapaxes write
        f32x4 acc2[2] = {};
        #pragma unroll 4
        for (int ks = 0; ks < 8; ks++) {
            bf16x8 a = YA8[ks * 64 + lane];
            #pragma unroll
            for (int n = 0; n < 2; n++) {
                bf16x8 b = B8n[((size_t)(w * 2 + n) * 8 + ks) * 64 + lane];
                acc2[n] = __builtin_amdgcn_mfma_f32_16x16x32_bf16(a, b, acc2[n], 0, 0, 0);
            }
        }
        int row = mt * 16 + rbase;
        #pragma unroll
        for (int n = 0; n < 2; n++) {
            int col = (w * 2 + n) * 16 + cl;
            float bv = bn[col];
            #pragma unroll
            for (int r = 0; r < 4; r++) {
                int grow = row + r;
                int bq = grow / TS, pp = grow - bq * TS;
                outp[((size_t)pp * NB + bq) * 128 + col] = acc2[n][r] + bv;
            }
        }
    }
}

// ---------------------------------------------------------------------------
// MFMA flash attention (unchanged, passing since round 9).
// ---------------------------------------------------------------------------
__global__ __launch_bounds__(256) void k_attn(
    const __bf16* __restrict__ qkv, const float* __restrict__ rel_bias,
    __bf16* __restrict__ PA)
{
    __shared__ __align__(16) __bf16 Kfr[4][64][8];
    __shared__ __align__(16) __bf16 Vpl[2][64][16];
    __shared__ __align__(16) __bf16 PT[4][64][16];
    __shared__ float bias_s[132];

    int bh = blockIdx.x, qt = 7 - blockIdx.y;   // heavy tiles first
    int b = bh >> 3, hh = bh & 7;
    int q0 = qt * 64;
    int t = threadIdx.x, lane = t & 63, w = t >> 6;
    int c = lane & 15, g = lane >> 4;

    const __bf16* base = qkv + (size_t)b * TS * 768 + hh * 32;

    if (t < 129) bias_s[t] = rel_bias[hh * 129 + t];

    bf16x8 aq = {};
    {
        int qi = q0 + 16 * w + c;
        if (qi < TS) aq = *(const bf16x8*)(base + (size_t)qi * 768 + 8 * g);
    }

    float lpart[4] = {0.f, 0.f, 0.f, 0.f};
    f32x4 O0 = {}, O1 = {};
    const float scale = 0.17677669529663687f;

    int nj = qt + 1;

    for (int it = 0; it < nj; it++) {
        int j0 = it * 64;
        __syncthreads();
        {
            int j = j0 + w * 16 + c;
            bf16x8 kv = {};
            if (j < TS) kv = *(const bf16x8*)(base + (size_t)j * 768 + 256 + 8 * g);
            *(bf16x8*)&Kfr[w][lane][0] = kv;
        }
        {
            int jl = t >> 2, dseg = t & 3;
            int j = j0 + jl;
            bf16x8 vv = {};
            if (j < TS) vv = *(const bf16x8*)(base + (size_t)j * 768 + 512 + 8 * dseg);
            *(bf16x8*)&Vpl[dseg >> 1][jl][(dseg & 1) * 8] = vv;
        }
        __syncthreads();

        f32x4 S[4];
        f32x4 zero = {};
        #pragma unroll
        for (int jt = 0; jt < 4; jt++) {
            bf16x8 bk = *(const bf16x8*)&Kfr[jt][lane][0];
            S[jt] = __builtin_amdgcn_mfma_f32_16x16x32_bf16(aq, bk, zero, 0, 0, 0);
        }

        #pragma unroll
        for (int jt = 0; jt < 4; jt++) {
            int j = j0 + jt * 16 + c;
            #pragma unroll
            for (int r = 0; r < 4; r++) {
                int i = q0 + 16 * w + 4 * g + r;
                int rel = j - i;
                rel = rel < -64 ? -64 : (rel > 64 ? 64 : rel);
                float sv = S[jt][r] * scale + bias_s[rel + 64];
                float pr = (j > i) ? 0.f : __expf(sv);
                S[jt][r] = pr;
                lpart[r] += pr;
            }
        }

        #pragma unroll
        for (int jt = 0; jt < 4; jt++) {
            bf16x4 pv;
            pv[0] = (__bf16)S[jt][0]; pv[1] = (__bf16)S[jt][1];
            pv[2] = (__bf16)S[jt][2]; pv[3] = (__bf16)S[jt][3];
            *(bf16x4*)&PT[w][jt * 16 + c][4 * g] = pv;
        }
        asm volatile("s_waitcnt lgkmcnt(0)" ::: "memory");
        __builtin_amdgcn_sched_barrier(0);

        f32x2 pa_lo[2], pa_hi[2], vb_lo[2][2], vb_hi[2][2];
        #pragma unroll
        for (int jb = 0; jb < 2; jb++) {
            unsigned pta = (unsigned)(uintptr_t)&PT[w][jb * 32 + 8 * g][0] + c * 8;
            asm volatile("ds_read_b64_tr_b16 %0, %1" : "=v"(pa_lo[jb]) : "v"(pta) : "memory");
            asm volatile("ds_read_b64_tr_b16 %0, %1 offset:128" : "=v"(pa_hi[jb]) : "v"(pta) : "memory");
            #pragma unroll
            for (int dh = 0; dh < 2; dh++) {
                unsigned vta = (unsigned)(uintptr_t)&Vpl[dh][jb * 32 + 8 * g][0] + c * 8;
                asm volatile("ds_read_b64_tr_b16 %0, %1" : "=v"(vb_lo[jb][dh]) : "v"(vta) : "memory");
                asm volatile("ds_read_b64_tr_b16 %0, %1 offset:128" : "=v"(vb_hi[jb][dh]) : "v"(vta) : "memory");
            }
        }
        asm volatile("s_waitcnt lgkmcnt(0)" ::: "memory");
        __builtin_amdgcn_sched_barrier(0);

        #pragma unroll
        for (int jb = 0; jb < 2; jb++) {
            f32x4 pc = {pa_lo[jb][0], pa_lo[jb][1], pa_hi[jb][0], pa_hi[jb][1]};
            bf16x8 pa = __builtin_bit_cast(bf16x8, pc);
            f32x4 v0c = {vb_lo[jb][0][0], vb_lo[jb][0][1], vb_hi[jb][0][0], vb_hi[jb][0][1]};
            f32x4 v1c = {vb_lo[jb][1][0], vb_lo[jb][1][1], vb_hi[jb][1][0], vb_hi[jb][1][1]};
            bf16x8 vb0 = __builtin_bit_cast(bf16x8, v0c);
            bf16x8 vb1 = __builtin_bit_cast(bf16x8, v1c);
            O0 = __builtin_amdgcn_mfma_f32_16x16x32_bf16(pa, vb0, O0, 0, 0, 0);
            O1 = __builtin_amdgcn_mfma_f32_16x16x32_bf16(pa, vb1, O1, 0, 0, 0);
        }
    }

    #pragma unroll
    for (int r = 0; r < 4; r++) {
        #pragma unroll
        for (int off = 1; off < 16; off <<= 1) lpart[r] += __shfl_xor(lpart[r], off, 64);
    }
    #pragma unroll
    for (int r = 0; r < 4; r++) {
        int i = q0 + 16 * w + 4 * g + r;
        if (i < TS) {
            float inv = 1.0f / lpart[r];
            int grow = b * TS + i;
            int mt = grow >> 4, rl = grow & 15;
            size_t fb = (size_t)(mt * 8 + hh) * 64;
            PA[(fb + ((c >> 3) & 1) * 16 + rl) * 8 + (c & 7)]       = (__bf16)(O0[r] * inv);
            PA[(fb + (2 + ((c >> 3) & 1)) * 16 + rl) * 8 + (c & 7)] = (__bf16)(O1[r] * inv);
        }
    }
}

extern "C" void kernel_launch(void* const* d_in, const int* in_sizes, int n_in,
                              void* d_out, int out_size, void* d_ws, size_t ws_size,
                              hipStream_t stream)
{
    const float* x        = (const float*)d_in[0];
    const float* ln1_g    = (const float*)d_in[1];
    const float* ln1_b    = (const float*)d_in[2];
    const float* proj_w   = (const float*)d_in[3];
    const float* proj_b   = (const float*)d_in[4];
    const float* ln2_g    = (const float*)d_in[5];
    const float* ln2_b    = (const float*)d_in[6];
    const float* rel_bias = (const float*)d_in[7];
    const float* ln_attn_g= (const float*)d_in[8];
    const float* ln_attn_b= (const float*)d_in[9];
    const float* qkv_w    = (const float*)d_in[10];
    const float* qkv_b    = (const float*)d_in[11];
    const float* out_w    = (const float*)d_in[12];
    const float* out_b    = (const float*)d_in[13];
    const float* ln_ff_g  = (const float*)d_in[14];
    const float* ln_ff_b  = (const float*)d_in[15];
    const float* ff1_w    = (const float*)d_in[16];
    const float* ff1_b    = (const float*)d_in[17];
    const float* ff2_w    = (const float*)d_in[18];
    const float* ff2_b    = (const float*)d_in[19];
    const float* fln_g    = (const float*)d_in[20];
    const float* fln_b    = (const float*)d_in[21];
    const float* op_w     = (const float*)d_in[22];
    const float* op_b     = (const float*)d_in[23];
    float* out = (float*)d_out;

    char* ws = (char*)d_ws;
    float*  h     = (float*)(ws);                      //  8,192,000 B
    __bf16* qkvb  = (__bf16*)(ws + 8192000);           // 12,288,000 B
    __bf16* PA    = (__bf16*)(ws + 20480000);          //  4,096,000 B
    __bf16* PBq   = (__bf16*)(ws + 24576000);          //  1,572,864 B
    __bf16* PBo   = (__bf16*)(ws + 26148864);          //    524,288 B
    __bf16* PB1   = (__bf16*)(ws + 26673152);          //  2,097,152 B
    __bf16* PB2   = (__bf16*)(ws + 28770304);          //  2,097,152 B
    __bf16* PBp   = (__bf16*)(ws + 30867456);          //    262,144 B
    __bf16* PBop  = (__bf16*)(ws + 31129600);          //     65,536 B

    // ---- all weight packs, one kernel ----
    k_pack_all<<<1616, 256, 0, stream>>>(qkv_w, out_w, ff1_w, ff2_w, proj_w, op_w,
                                         PBq, PBo, PB1, PB2, PBp, PBop);

    // ---- patch fused (+ qkv for layer 0) ----
    k_patchfused<<<250, 256, 0, stream>>>(x, ln1_g, ln1_b, PBp, proj_b, h,
                                          ln2_g, ln2_b, ln_attn_g, ln_attn_b,
                                          PBq, qkv_b, qkvb);

    for (int l = 0; l < 4; l++) {
        dim3 ag(NB * NHEAD, 8);
        k_attn<<<ag, 256, 0, stream>>>(qkvb, rel_bias, PA);
        // out-proj + residual -> h, LN_ff -> PA
        k_outproj<<<500, 256, 0, stream>>>(PA, PBo + (size_t)l * 65536, out_b + l * 256,
                                           h, PA, ln_ff_g + l * 256, ln_ff_b + l * 256);
        if (l < 3) {
            // ff fused + LN_attn[l+1] + qkv[l+1] -> qkvb
            k_fffused<0><<<500, 256, 0, stream>>>(PA, PB1 + (size_t)l * 262144, ff1_b + l * 1024,
                                                  PB2 + (size_t)l * 262144, ff2_b + l * 256, h,
                                                  ln_attn_g + (l + 1) * 256, ln_attn_b + (l + 1) * 256,
                                                  PBq + (size_t)(l + 1) * 196608, qkv_b + (l + 1) * 768,
                                                  qkvb, nullptr);
        } else {
            // ff fused + fln + final projection -> out
            k_fffused<1><<<500, 256, 0, stream>>>(PA, PB1 + (size_t)l * 262144, ff1_b + l * 1024,
                                                  PB2 + (size_t)l * 262144, ff2_b + l * 256, h,
                                                  fln_g, fln_b,
                                                  PBop, op_b, nullptr, out);
        }
    }
}

// Round 14
// 285.307 us; speedup vs baseline: 1.2424x; 1.2157x over previous
//
#include <hip/hip_runtime.h>

#define TS 500      // n_patch (sequence length)
#define NB 16       // batch
#define NROW 8000   // NB * TS
#define DMODEL 256
#define NHEAD 8
#define HDIM 32
#define FFD 1024

typedef __bf16 bf16x8 __attribute__((ext_vector_type(8)));
typedef __bf16 bf16x4 __attribute__((ext_vector_type(4)));
typedef float  f32x4  __attribute__((ext_vector_type(4)));
typedef float  f32x2  __attribute__((ext_vector_type(2)));

__device__ __forceinline__ float wred_sum(float v) {
    #pragma unroll
    for (int off = 32; off; off >>= 1) v += __shfl_xor(v, off, 64);
    return v;
}

// A-fragment scatter store (global): element (grow, col) of [8000][K] bf16,
// KS = K/32 fragments per row-tile.
__device__ __forceinline__ void pa_store(__bf16* __restrict__ PA, int KS,
                                         int grow, int col, float y) {
    int mt = grow >> 4, rl = grow & 15;
    size_t idx = ((size_t)(mt * KS + (col >> 5)) * 64 + ((col >> 3) & 3) * 16 + rl) * 8 + (col & 7);
    PA[idx] = (__bf16)y;
}

// A-fragment scatter store (LDS, local row 0..R*16-1, KS=8)
__device__ __forceinline__ void ya_store(__bf16* __restrict__ YA,
                                         int lrow, int col, float y) {
    int mtl = lrow >> 4, rl = lrow & 15;
    int idx = (((mtl * 8 + (col >> 5)) * 64) + ((col >> 3) & 3) * 16 + rl) * 8 + (col & 7);
    YA[idx] = (__bf16)y;
}

// ---------------------------------------------------------------------------
// All weight packs in ONE kernel. Flat grid of 1616 blocks, range dispatch.
// ---------------------------------------------------------------------------
__global__ __launch_bounds__(256) void k_pack_all(
    const float* __restrict__ qkv_w, const float* __restrict__ out_w,
    const float* __restrict__ ff1_w, const float* __restrict__ ff2_w,
    const float* __restrict__ proj_w, const float* __restrict__ op_w,
    __bf16* __restrict__ PBq, __bf16* __restrict__ PBo,
    __bf16* __restrict__ PB1, __bf16* __restrict__ PB2,
    __bf16* __restrict__ PBp, __bf16* __restrict__ PBop)
{
    int bid = blockIdx.x;
    const float* W; __bf16* PB; int KS, NT, wLS, pLS, l, bx;
    if (bid < 384)       { W = qkv_w;  PB = PBq;  KS = 8;  NT = 48; wLS = 196608; pLS = 196608; l = bid / 96;           bx = bid % 96; }
    else if (bid < 512)  { W = out_w;  PB = PBo;  KS = 8;  NT = 16; wLS = 65536;  pLS = 65536;  l = (bid - 384) / 32;   bx = (bid - 384) % 32; }
    else if (bid < 1024) { W = ff1_w;  PB = PB1;  KS = 8;  NT = 64; wLS = 262144; pLS = 262144; l = (bid - 512) / 128;  bx = (bid - 512) % 128; }
    else if (bid < 1536) { W = ff2_w;  PB = PB2;  KS = 32; NT = 16; wLS = 262144; pLS = 262144; l = (bid - 1024) / 128; bx = (bid - 1024) % 128; }
    else if (bid < 1600) { W = proj_w; PB = PBp;  KS = 16; NT = 16; wLS = 0;      pLS = 0;      l = 0;                  bx = bid - 1536; }
    else                 { W = op_w;   PB = PBop; KS = 8;  NT = 8;  wLS = 0;      pLS = 0;      l = 0;                  bx = bid - 1600; }

    int gid = bx * 256 + threadIdx.x;
    if (gid >= NT * KS * 64) return;
    int lane = gid & 63;
    int ks = (gid >> 6) % KS;
    int nt = (gid >> 6) / KS;
    int N = NT * 16;
    int k0 = ks * 32 + (lane >> 4) * 8;
    int col = nt * 16 + (lane & 15);
    const float* src = W + (size_t)l * wLS;
    bf16x8 v;
    #pragma unroll
    for (int j = 0; j < 8; j++) v[j] = (__bf16)src[(size_t)(k0 + j) * N + col];
    *(bf16x8*)(PB + (size_t)l * pLS + ((size_t)(nt * KS + ks) * 64 + lane) * 8) = v;
}

// ---------------------------------------------------------------------------
// Patch stage FUSED + qkv[0] (unchanged from round 13, passing).
// ---------------------------------------------------------------------------
__global__ __launch_bounds__(256) void k_patchfused(
    const float* __restrict__ x, const float* __restrict__ g1, const float* __restrict__ b1,
    const __bf16* __restrict__ PBp, const float* __restrict__ bias,
    float* __restrict__ h,
    const float* __restrict__ gam, const float* __restrict__ bet,
    const float* __restrict__ gam2, const float* __restrict__ bet2,
    const __bf16* __restrict__ PBq0, const float* __restrict__ qb0,
    __bf16* __restrict__ qkvb)
{
    __shared__ __align__(16) __bf16 As[2][16][64][8];   // 32 KB; reused as YA
    __shared__ float redS[4][32];
    __shared__ float redQ[4][32];
    int t = threadIdx.x, lane = t & 63, w = t >> 6;
    int row0 = blockIdx.x * 32;

    for (int rr = 0; rr < 8; rr++) {
        int lrow = w * 8 + rr;
        int row = row0 + lrow;
        int b = row / TS, pp = row - b * TS;
        int kb = lane * 8;
        const float* src = x + ((size_t)(pp * 4 + (kb >> 7)) * NB + b) * 128 + (kb & 127);
        float4 lo = *(const float4*)src;
        float4 hi = *(const float4*)(src + 4);
        float v[8] = {lo.x, lo.y, lo.z, lo.w, hi.x, hi.y, hi.z, hi.w};
        float sm_ = 0.f;
        #pragma unroll
        for (int j = 0; j < 8; j++) sm_ += v[j];
        sm_ = wred_sum(sm_);
        float mu = sm_ * (1.0f / 512.0f);
        float q = 0.f;
        #pragma unroll
        for (int j = 0; j < 8; j++) { float d = v[j] - mu; q += d * d; }
        q = wred_sum(q);
        float rs = rsqrtf(q * (1.0f / 512.0f) + 1e-6f);
        float4 gl = *(const float4*)(g1 + kb), gh = *(const float4*)(g1 + kb + 4);
        float4 bl = *(const float4*)(b1 + kb), bh = *(const float4*)(b1 + kb + 4);
        float gg[8] = {gl.x, gl.y, gl.z, gl.w, gh.x, gh.y, gh.z, gh.w};
        float bbv[8] = {bl.x, bl.y, bl.z, bl.w, bh.x, bh.y, bh.z, bh.w};
        bf16x8 yv;
        #pragma unroll
        for (int j = 0; j < 8; j++) yv[j] = (__bf16)((v[j] - mu) * rs * gg[j] + bbv[j]);
        *(bf16x8*)&As[lrow >> 4][lane >> 2][(lane & 3) * 16 + (lrow & 15)][0] = yv;
    }
    __syncthreads();

    const bf16x8* B8 = (const bf16x8*)PBp;
    f32x4 acc[2][4] = {};
    #pragma unroll 8
    for (int ks = 0; ks < 16; ks++) {
        bf16x8 a0 = *(const bf16x8*)&As[0][ks][lane][0];
        bf16x8 a1 = *(const bf16x8*)&As[1][ks][lane][0];
        #pragma unroll
        for (int n = 0; n < 4; n++) {
            bf16x8 b = B8[((size_t)(w * 4 + n) * 16 + ks) * 64 + lane];
            acc[0][n] = __builtin_amdgcn_mfma_f32_16x16x32_bf16(a0, b, acc[0][n], 0, 0, 0);
            acc[1][n] = __builtin_amdgcn_mfma_f32_16x16x32_bf16(a1, b, acc[1][n], 0, 0, 0);
        }
    }

    int g_ = lane >> 4, cl = lane & 15;
    int rbase = g_ * 4;
    float gamv[4], betv[4], gam2v[4], bet2v[4];
    #pragma unroll
    for (int n = 0; n < 4; n++) {
        int col = (w * 4 + n) * 16 + cl;
        float bv = bias[col];
        gamv[n] = gam[col]; betv[n] = bet[col];
        gam2v[n] = gam2[col]; bet2v[n] = bet2[col];
        #pragma unroll
        for (int m = 0; m < 2; m++)
            #pragma unroll
            for (int r = 0; r < 4; r++) acc[m][n][r] += bv;
    }
    float mu[2][4], rstd[2][4];
    {
        float ps[2][4];
        #pragma unroll
        for (int m = 0; m < 2; m++)
            #pragma unroll
            for (int r = 0; r < 4; r++) {
                float s2 = acc[m][0][r] + acc[m][1][r] + acc[m][2][r] + acc[m][3][r];
                #pragma unroll
                for (int off = 1; off < 16; off <<= 1) s2 += __shfl_xor(s2, off, 64);
                ps[m][r] = s2;
            }
        if (cl == 0)
            #pragma unroll
            for (int m = 0; m < 2; m++)
                #pragma unroll
                for (int r = 0; r < 4; r++) redS[w][m * 16 + rbase + r] = ps[m][r];
        __syncthreads();
        #pragma unroll
        for (int m = 0; m < 2; m++)
            #pragma unroll
            for (int r = 0; r < 4; r++) {
                int lr = m * 16 + rbase + r;
                mu[m][r] = (redS[0][lr] + redS[1][lr] + redS[2][lr] + redS[3][lr]) * (1.0f / 256.0f);
            }
        float pq[2][4];
        #pragma unroll
        for (int m = 0; m < 2; m++)
            #pragma unroll
            for (int r = 0; r < 4; r++) {
                float s2 = 0.f;
                #pragma unroll
                for (int n = 0; n < 4; n++) { float d = acc[m][n][r] - mu[m][r]; s2 += d * d; }
                #pragma unroll
                for (int off = 1; off < 16; off <<= 1) s2 += __shfl_xor(s2, off, 64);
                pq[m][r] = s2;
            }
        if (cl == 0)
            #pragma unroll
            for (int m = 0; m < 2; m++)
                #pragma unroll
                for (int r = 0; r < 4; r++) redQ[w][m * 16 + rbase + r] = pq[m][r];
        __syncthreads();
        #pragma unroll
        for (int m = 0; m < 2; m++)
            #pragma unroll
            for (int r = 0; r < 4; r++) {
                int lr = m * 16 + rbase + r;
                float var = (redQ[0][lr] + redQ[1][lr] + redQ[2][lr] + redQ[3][lr]) * (1.0f / 256.0f);
                rstd[m][r] = rsqrtf(var + 1e-6f);
            }
    }
    float ps2[2][4];
    #pragma unroll
    for (int m = 0; m < 2; m++) {
        int row = row0 + m * 16 + rbase;
        #pragma unroll
        for (int r = 0; r < 4; r++) {
            float s2 = 0.f;
            #pragma unroll
            for (int n = 0; n < 4; n++) {
                int col = (w * 4 + n) * 16 + cl;
                float y1 = (acc[m][n][r] - mu[m][r]) * rstd[m][r] * gamv[n] + betv[n];
                h[(size_t)(row + r) * 256 + col] = y1;
                s2 += y1;
            }
            #pragma unroll
            for (int off = 1; off < 16; off <<= 1) s2 += __shfl_xor(s2, off, 64);
            ps2[m][r] = s2;
        }
    }
    if (cl == 0)
        #pragma unroll
        for (int m = 0; m < 2; m++)
            #pragma unroll
            for (int r = 0; r < 4; r++) redS[w][m * 16 + rbase + r] = ps2[m][r];
    __syncthreads();
    float mu2[2][4], rstd2[2][4];
    #pragma unroll
    for (int m = 0; m < 2; m++)
        #pragma unroll
        for (int r = 0; r < 4; r++) {
            int lr = m * 16 + rbase + r;
            mu2[m][r] = (redS[0][lr] + redS[1][lr] + redS[2][lr] + redS[3][lr]) * (1.0f / 256.0f);
        }
    float pq2[2][4];
    #pragma unroll
    for (int m = 0; m < 2; m++)
        #pragma unroll
        for (int r = 0; r < 4; r++) {
            float s2 = 0.f;
            #pragma unroll
            for (int n = 0; n < 4; n++) {
                float y1 = (acc[m][n][r] - mu[m][r]) * rstd[m][r] * gamv[n] + betv[n];
                float d = y1 - mu2[m][r];
                s2 += d * d;
            }
            #pragma unroll
            for (int off = 1; off < 16; off <<= 1) s2 += __shfl_xor(s2, off, 64);
            pq2[m][r] = s2;
        }
    if (cl == 0)
        #pragma unroll
        for (int m = 0; m < 2; m++)
            #pragma unroll
            for (int r = 0; r < 4; r++) redQ[w][m * 16 + rbase + r] = pq2[m][r];
    __syncthreads();
    #pragma unroll
    for (int m = 0; m < 2; m++)
        #pragma unroll
        for (int r = 0; r < 4; r++) {
            int lr = m * 16 + rbase + r;
            float var = (redQ[0][lr] + redQ[1][lr] + redQ[2][lr] + redQ[3][lr]) * (1.0f / 256.0f);
            rstd2[m][r] = rsqrtf(var + 1e-5f);
        }
    __bf16* YA = &As[0][0][0][0];   // [2][8][64][8]
    #pragma unroll
    for (int m = 0; m < 2; m++) {
        #pragma unroll
        for (int n = 0; n < 4; n++) {
            int col = (w * 4 + n) * 16 + cl;
            #pragma unroll
            for (int r = 0; r < 4; r++) {
                float y1 = (acc[m][n][r] - mu[m][r]) * rstd[m][r] * gamv[n] + betv[n];
                float y2 = (y1 - mu2[m][r]) * rstd2[m][r] * gam2v[n] + bet2v[n];
                ya_store(YA, m * 16 + rbase + r, col, y2);
            }
        }
    }
    __syncthreads();

    const bf16x8* YA8 = (const bf16x8*)YA;
    const bf16x8* B8q = (const bf16x8*)PBq0;
    for (int m = 0; m < 2; m++) {
        f32x4 acc2[12] = {};
        for (int ks = 0; ks < 8; ks++) {
            bf16x8 a = YA8[(m * 8 + ks) * 64 + lane];
            #pragma unroll
            for (int n = 0; n < 12; n++) {
                bf16x8 b = B8q[((size_t)(w * 12 + n) * 8 + ks) * 64 + lane];
                acc2[n] = __builtin_amdgcn_mfma_f32_16x16x32_bf16(a, b, acc2[n], 0, 0, 0);
            }
        }
        int row = row0 + m * 16 + rbase;
        #pragma unroll
        for (int n = 0; n < 12; n++) {
            int col = (w * 12 + n) * 16 + cl;
            float bv = qb0[col];
            #pragma unroll
            for (int r = 0; r < 4; r++)
                qkvb[(size_t)(row + r) * 768 + col] = (__bf16)(acc2[n][r] + bv);
        }
    }
}

// ---------------------------------------------------------------------------
// Out-projection GEMM (EPI4), 512 threads / 8 waves: wave owns 2 n-tiles.
// h += acc+bias; LN(h) -> PA. MT=1, grid 500.
// ---------------------------------------------------------------------------
__global__ __launch_bounds__(512) void k_outproj(
    const __bf16* __restrict__ PA, const __bf16* __restrict__ PB,
    const float* __restrict__ bias, float* __restrict__ dst,
    __bf16* __restrict__ dstb,
    const float* __restrict__ gam, const float* __restrict__ bet)
{
    __shared__ float redS[8][16];
    __shared__ float redQ[8][16];
    int t = threadIdx.x, lane = t & 63, w = t >> 6;   // w in 0..7
    int mt0 = blockIdx.x;

    const bf16x8* A8 = (const bf16x8*)PA;
    const bf16x8* B8 = (const bf16x8*)PB;

    f32x4 acc[2] = {};
    #pragma unroll 8
    for (int ks = 0; ks < 8; ks++) {
        bf16x8 a = A8[((size_t)mt0 * 8 + ks) * 64 + lane];
        #pragma unroll
        for (int n = 0; n < 2; n++) {
            bf16x8 b = B8[((size_t)(w * 2 + n) * 8 + ks) * 64 + lane];
            acc[n] = __builtin_amdgcn_mfma_f32_16x16x32_bf16(a, b, acc[n], 0, 0, 0);
        }
    }

    int g_ = lane >> 4, cl = lane & 15;
    int rbase = g_ * 4;
    float gamv[2], betv[2];
    #pragma unroll
    for (int n = 0; n < 2; n++) {
        int col = (w * 2 + n) * 16 + cl;
        float bv = bias[col];
        gamv[n] = gam[col]; betv[n] = bet[col];
        int row = mt0 * 16 + rbase;
        #pragma unroll
        for (int r = 0; r < 4; r++) {
            float v = acc[n][r] + bv + dst[(size_t)(row + r) * 256 + col];
            dst[(size_t)(row + r) * 256 + col] = v;
            acc[n][r] = v;
        }
    }
    float mu[4], rstd[4];
    {
        float ps[4];
        #pragma unroll
        for (int r = 0; r < 4; r++) {
            float s2 = acc[0][r] + acc[1][r];
            #pragma unroll
            for (int off = 1; off < 16; off <<= 1) s2 += __shfl_xor(s2, off, 64);
            ps[r] = s2;
        }
        if (cl == 0)
            #pragma unroll
            for (int r = 0; r < 4; r++) redS[w][rbase + r] = ps[r];
        __syncthreads();
        #pragma unroll
        for (int r = 0; r < 4; r++) {
            int lr = rbase + r;
            float s2 = 0.f;
            #pragma unroll
            for (int ww = 0; ww < 8; ww++) s2 += redS[ww][lr];
            mu[r] = s2 * (1.0f / 256.0f);
        }
        float pq[4];
        #pragma unroll
        for (int r = 0; r < 4; r++) {
            float s2 = 0.f;
            #pragma unroll
            for (int n = 0; n < 2; n++) { float d = acc[n][r] - mu[r]; s2 += d * d; }
            #pragma unroll
            for (int off = 1; off < 16; off <<= 1) s2 += __shfl_xor(s2, off, 64);
            pq[r] = s2;
        }
        if (cl == 0)
            #pragma unroll
            for (int r = 0; r < 4; r++) redQ[w][rbase + r] = pq[r];
        __syncthreads();
        #pragma unroll
        for (int r = 0; r < 4; r++) {
            int lr = rbase + r;
            float s2 = 0.f;
            #pragma unroll
            for (int ww = 0; ww < 8; ww++) s2 += redQ[ww][lr];
            rstd[r] = rsqrtf(s2 * (1.0f / 256.0f) + 1e-5f);
        }
    }
    int row = mt0 * 16 + rbase;
    #pragma unroll
    for (int n = 0; n < 2; n++) {
        int col = (w * 2 + n) * 16 + cl;
        #pragma unroll
        for (int r = 0; r < 4; r++) {
            float y = (acc[n][r] - mu[r]) * rstd[r] * gamv[n] + betv[n];
            pa_store(dstb, 8, row + r, col, y);
        }
    }
}

// ---------------------------------------------------------------------------
// FF block FUSED + next GEMM, 512 threads / 8 waves, 16 rows/block, grid 500.
// Phase A: wave owns 128 ff1 cols (8 n-tiles). Phase B: wave owns 32 ff2 cols.
// MODE 0 tail: qkv[l+1] (wave owns 6 n-tiles). MODE 1 tail: final proj (1).
// ---------------------------------------------------------------------------
template<int MODE>
__global__ __launch_bounds__(512) void k_fffused(
    const __bf16* __restrict__ PA, const __bf16* __restrict__ PB1,
    const float* __restrict__ b1, const __bf16* __restrict__ PB2,
    const float* __restrict__ b2, float* __restrict__ h,
    const float* __restrict__ gam, const float* __restrict__ bet,
    const __bf16* __restrict__ PBn, const float* __restrict__ bn,
    __bf16* __restrict__ qkvb, float* __restrict__ outp)
{
    __shared__ __align__(16) __bf16 F1T[1024][16];   // 32 KB; head reused as YA
    __shared__ float redS[8][16];
    __shared__ float redQ[8][16];
    int t = threadIdx.x, lane = t & 63, w = t >> 6;  // w in 0..7
    int mt = blockIdx.x;
    int g_ = lane >> 4, cl = lane & 15, rbase = g_ * 4;

    const bf16x8* A8 = (const bf16x8*)PA;
    const bf16x8* B81 = (const bf16x8*)PB1;
    const bf16x8* B82 = (const bf16x8*)PB2;

    // ---- Phase A: ff1, wave w covers cols [w*128, w*128+128) ----
    f32x4 acc1[8] = {};
    #pragma unroll 2
    for (int ks = 0; ks < 8; ks++) {
        bf16x8 a = A8[((size_t)mt * 8 + ks) * 64 + lane];
        #pragma unroll
        for (int n = 0; n < 8; n++) {
            bf16x8 b = B81[((size_t)(w * 8 + n) * 8 + ks) * 64 + lane];
            acc1[n] = __builtin_amdgcn_mfma_f32_16x16x32_bf16(a, b, acc1[n], 0, 0, 0);
        }
    }
    #pragma unroll
    for (int n = 0; n < 8; n++) {
        int col = (w * 8 + n) * 16 + cl;
        float bv = b1[col];
        bf16x4 pv;
        #pragma unroll
        for (int r = 0; r < 4; r++) {
            float xx = acc1[n][r] + bv;
            pv[r] = (__bf16)(0.5f * xx * (1.0f + erff(xx * 0.70710678118654752f)));
        }
        *(bf16x4*)&F1T[col][rbase] = pv;
    }
    __syncthreads();

    // ---- Phase B: ff2, K=1024; A-frags via tr_b16; wave owns 2 n-tiles ----
    f32x4 acc[2] = {};
    for (int kb = 0; kb < 8; kb++) {
        f32x2 lo[4], hi[4];
        #pragma unroll
        for (int q = 0; q < 4; q++) {
            unsigned ta = (unsigned)(uintptr_t)&F1T[(kb * 4 + q) * 32 + 8 * g_][0] + cl * 8;
            asm volatile("ds_read_b64_tr_b16 %0, %1" : "=v"(lo[q]) : "v"(ta) : "memory");
            asm volatile("ds_read_b64_tr_b16 %0, %1 offset:128" : "=v"(hi[q]) : "v"(ta) : "memory");
        }
        asm volatile("s_waitcnt lgkmcnt(0)" ::: "memory");
        __builtin_amdgcn_sched_barrier(0);
        #pragma unroll
        for (int q = 0; q < 4; q++) {
            int ks = kb * 4 + q;
            f32x4 pc = {lo[q][0], lo[q][1], hi[q][0], hi[q][1]};
            bf16x8 a = __builtin_bit_cast(bf16x8, pc);
            #pragma unroll
            for (int n = 0; n < 2; n++) {
                bf16x8 b = B82[((size_t)(w * 2 + n) * 32 + ks) * 64 + lane];
                acc[n] = __builtin_amdgcn_mfma_f32_16x16x32_bf16(a, b, acc[n], 0, 0, 0);
            }
        }
    }

    // ---- EPI: +b2, residual -> h, LN -> YA (LDS) ----
    float gamv[2], betv[2];
    #pragma unroll
    for (int n = 0; n < 2; n++) {
        int col = (w * 2 + n) * 16 + cl;
        float bv = b2[col];
        gamv[n] = gam[col]; betv[n] = bet[col];
        int row = mt * 16 + rbase;
        #pragma unroll
        for (int r = 0; r < 4; r++) {
            float v = acc[n][r] + bv + h[(size_t)(row + r) * 256 + col];
            h[(size_t)(row + r) * 256 + col] = v;
            acc[n][r] = v;
        }
    }
    float mu[4], rstd[4];
    {
        float ps[4];
        #pragma unroll
        for (int r = 0; r < 4; r++) {
            float s2 = acc[0][r] + acc[1][r];
            #pragma unroll
            for (int off = 1; off < 16; off <<= 1) s2 += __shfl_xor(s2, off, 64);
            ps[r] = s2;
        }
        if (cl == 0)
            #pragma unroll
            for (int r = 0; r < 4; r++) redS[w][rbase + r] = ps[r];
        __syncthreads();
        #pragma unroll
        for (int r = 0; r < 4; r++) {
            int lr = rbase + r;
            float s2 = 0.f;
            #pragma unroll
            for (int ww = 0; ww < 8; ww++) s2 += redS[ww][lr];
            mu[r] = s2 * (1.0f / 256.0f);
        }
        float pq[4];
        #pragma unroll
        for (int r = 0; r < 4; r++) {
            float s2 = 0.f;
            #pragma unroll
            for (int n = 0; n < 2; n++) { float d = acc[n][r] - mu[r]; s2 += d * d; }
            #pragma unroll
            for (int off = 1; off < 16; off <<= 1) s2 += __shfl_xor(s2, off, 64);
            pq[r] = s2;
        }
        if (cl == 0)
            #pragma unroll
            for (int r = 0; r < 4; r++) redQ[w][rbase + r] = pq[r];
        __syncthreads();   // also guarantees all waves done reading F1T
        #pragma unroll
        for (int r = 0; r < 4; r++) {
            int lr = rbase + r;
            float s2 = 0.f;
            #pragma unroll
            for (int ww = 0; ww < 8; ww++) s2 += redQ[ww][lr];
            rstd[r] = rsqrtf(s2 * (1.0f / 256.0f) + 1e-5f);
        }
    }
    // y -> LDS A-frags (reuse F1T head: [8][64][8] = 8 KB)
    __bf16* YA = &F1T[0][0];
    #pragma unroll
    for (int n = 0; n < 2; n++) {
        int col = (w * 2 + n) * 16 + cl;
        #pragma unroll
        for (int r = 0; r < 4; r++) {
            float y = (acc[n][r] - mu[r]) * rstd[r] * gamv[n] + betv[n];
            ya_store(YA, rbase + r, col, y);
        }
    }
    __syncthreads();

    // ---- tail GEMM from YA ----
    const bf16x8* YA8 = (const bf16x8*)YA;
    const bf16x8* B8n = (const bf16x8*)PBn;
    if constexpr (MODE == 0) {
        // qkv[l+1]: 48 n-tiles, wave owns 6
        f32x4 acc2[6] = {};
        for (int ks = 0; ks < 8; ks++) {
            bf16x8 a = YA8[ks * 64 + lane];
            #pragma unroll
            for (int n = 0; n < 6; n++) {
                bf16x8 b = B8n[((size_t)(w * 6 + n) * 8 + ks) * 64 + lane];
                acc2[n] = __builtin_amdgcn_mfma_f32_16x16x32_bf16(a, b, acc2[n], 0, 0, 0);
            }
        }
        int row = mt * 16 + rbase;
        #pragma unroll
        for (int n = 0; n < 6; n++) {
            int col = (w * 6 + n) * 16 + cl;
            float bv = bn[col];
            #pragma unroll
            for (int r = 0; r < 4; r++)
                qkvb[(size_t)(row + r) * 768 + col] = (__bf16)(acc2[n][r] + bv);
        }
    } else {
        // final projection: 8 n-tiles, wave owns 1; swapaxes write
        f32x4 acc2 = {};
        #pragma unroll 4
        for (int ks = 0; ks < 8; ks++) {
            bf16x8 a = YA8[ks * 64 + lane];
            bf16x8 b = B8n[((size_t)w * 8 + ks) * 64 + lane];
            acc2 = __builtin_amdgcn_mfma_f32_16x16x32_bf16(a, b, acc2, 0, 0, 0);
        }
        int row = mt * 16 + rbase;
        int col = w * 16 + cl;
        float bv = bn[col];
        #pragma unroll
        for (int r = 0; r < 4; r++) {
            int grow = row + r;
            int bq = grow / TS, pp = grow - bq * TS;
            outp[((size_t)pp * NB + bq) * 128 + col] = acc2[r] + bv;
        }
    }
}

// ---------------------------------------------------------------------------
// MFMA flash attention (unchanged, passing since round 9).
// ---------------------------------------------------------------------------
__global__ __launch_bounds__(256) void k_attn(
    const __bf16* __restrict__ qkv, const float* __restrict__ rel_bias,
    __bf16* __restrict__ PA)
{
    __shared__ __align__(16) __bf16 Kfr[4][64][8];
    __shared__ __align__(16) __bf16 Vpl[2][64][16];
    __shared__ __align__(16) __bf16 PT[4][64][16];
    __shared__ float bias_s[132];

    int bh = blockIdx.x, qt = 7 - blockIdx.y;   // heavy tiles first
    int b = bh >> 3, hh = bh & 7;
    int q0 = qt * 64;
    int t = threadIdx.x, lane = t & 63, w = t >> 6;
    int c = lane & 15, g = lane >> 4;

    const __bf16* base = qkv + (size_t)b * TS * 768 + hh * 32;

    if (t < 129) bias_s[t] = rel_bias[hh * 129 + t];

    bf16x8 aq = {};
    {
        int qi = q0 + 16 * w + c;
        if (qi < TS) aq = *(const bf16x8*)(base + (size_t)qi * 768 + 8 * g);
    }

    float lpart[4] = {0.f, 0.f, 0.f, 0.f};
    f32x4 O0 = {}, O1 = {};
    const float scale = 0.17677669529663687f;

    int nj = qt + 1;

    for (int it = 0; it < nj; it++) {
        int j0 = it * 64;
        __syncthreads();
        {
            int j = j0 + w * 16 + c;
            bf16x8 kv = {};
            if (j < TS) kv = *(const bf16x8*)(base + (size_t)j * 768 + 256 + 8 * g);
            *(bf16x8*)&Kfr[w][lane][0] = kv;
        }
        {
            int jl = t >> 2, dseg = t & 3;
            int j = j0 + jl;
            bf16x8 vv = {};
            if (j < TS) vv = *(const bf16x8*)(base + (size_t)j * 768 + 512 + 8 * dseg);
            *(bf16x8*)&Vpl[dseg >> 1][jl][(dseg & 1) * 8] = vv;
        }
        __syncthreads();

        f32x4 S[4];
        f32x4 zero = {};
        #pragma unroll
        for (int jt = 0; jt < 4; jt++) {
            bf16x8 bk = *(const bf16x8*)&Kfr[jt][lane][0];
            S[jt] = __builtin_amdgcn_mfma_f32_16x16x32_bf16(aq, bk, zero, 0, 0, 0);
        }

        #pragma unroll
        for (int jt = 0; jt < 4; jt++) {
            int j = j0 + jt * 16 + c;
            #pragma unroll
            for (int r = 0; r < 4; r++) {
                int i = q0 + 16 * w + 4 * g + r;
                int rel = j - i;
                rel = rel < -64 ? -64 : (rel > 64 ? 64 : rel);
                float sv = S[jt][r] * scale + bias_s[rel + 64];
                float pr = (j > i) ? 0.f : __expf(sv);
                S[jt][r] = pr;
                lpart[r] += pr;
            }
        }

        #pragma unroll
        for (int jt = 0; jt < 4; jt++) {
            bf16x4 pv;
            pv[0] = (__bf16)S[jt][0]; pv[1] = (__bf16)S[jt][1];
            pv[2] = (__bf16)S[jt][2]; pv[3] = (__bf16)S[jt][3];
            *(bf16x4*)&PT[w][jt * 16 + c][4 * g] = pv;
        }
        asm volatile("s_waitcnt lgkmcnt(0)" ::: "memory");
        __builtin_amdgcn_sched_barrier(0);

        f32x2 pa_lo[2], pa_hi[2], vb_lo[2][2], vb_hi[2][2];
        #pragma unroll
        for (int jb = 0; jb < 2; jb++) {
            unsigned pta = (unsigned)(uintptr_t)&PT[w][jb * 32 + 8 * g][0] + c * 8;
            asm volatile("ds_read_b64_tr_b16 %0, %1" : "=v"(pa_lo[jb]) : "v"(pta) : "memory");
            asm volatile("ds_read_b64_tr_b16 %0, %1 offset:128" : "=v"(pa_hi[jb]) : "v"(pta) : "memory");
            #pragma unroll
            for (int dh = 0; dh < 2; dh++) {
                unsigned vta = (unsigned)(uintptr_t)&Vpl[dh][jb * 32 + 8 * g][0] + c * 8;
                asm volatile("ds_read_b64_tr_b16 %0, %1" : "=v"(vb_lo[jb][dh]) : "v"(vta) : "memory");
                asm volatile("ds_read_b64_tr_b16 %0, %1 offset:128" : "=v"(vb_hi[jb][dh]) : "v"(vta) : "memory");
            }
        }
        asm volatile("s_waitcnt lgkmcnt(0)" ::: "memory");
        __builtin_amdgcn_sched_barrier(0);

        #pragma unroll
        for (int jb = 0; jb < 2; jb++) {
            f32x4 pc = {pa_lo[jb][0], pa_lo[jb][1], pa_hi[jb][0], pa_hi[jb][1]};
            bf16x8 pa = __builtin_bit_cast(bf16x8, pc);
            f32x4 v0c = {vb_lo[jb][0][0], vb_lo[jb][0][1], vb_hi[jb][0][0], vb_hi[jb][0][1]};
            f32x4 v1c = {vb_lo[jb][1][0], vb_lo[jb][1][1], vb_hi[jb][1][0], vb_hi[jb][1][1]};
            bf16x8 vb0 = __builtin_bit_cast(bf16x8, v0c);
            bf16x8 vb1 = __builtin_bit_cast(bf16x8, v1c);
            O0 = __builtin_amdgcn_mfma_f32_16x16x32_bf16(pa, vb0, O0, 0, 0, 0);
            O1 = __builtin_amdgcn_mfma_f32_16x16x32_bf16(pa, vb1, O1, 0, 0, 0);
        }
    }

    #pragma unroll
    for (int r = 0; r < 4; r++) {
        #pragma unroll
        for (int off = 1; off < 16; off <<= 1) lpart[r] += __shfl_xor(lpart[r], off, 64);
    }
    #pragma unroll
    for (int r = 0; r < 4; r++) {
        int i = q0 + 16 * w + 4 * g + r;
        if (i < TS) {
            float inv = 1.0f / lpart[r];
            int grow = b * TS + i;
            int mt = grow >> 4, rl = grow & 15;
            size_t fb = (size_t)(mt * 8 + hh) * 64;
            PA[(fb + ((c >> 3) & 1) * 16 + rl) * 8 + (c & 7)]       = (__bf16)(O0[r] * inv);
            PA[(fb + (2 + ((c >> 3) & 1)) * 16 + rl) * 8 + (c & 7)] = (__bf16)(O1[r] * inv);
        }
    }
}

extern "C" void kernel_launch(void* const* d_in, const int* in_sizes, int n_in,
                              void* d_out, int out_size, void* d_ws, size_t ws_size,
                              hipStream_t stream)
{
    const float* x        = (const float*)d_in[0];
    const float* ln1_g    = (const float*)d_in[1];
    const float* ln1_b    = (const float*)d_in[2];
    const float* proj_w   = (const float*)d_in[3];
    const float* proj_b   = (const float*)d_in[4];
    const float* ln2_g    = (const float*)d_in[5];
    const float* ln2_b    = (const float*)d_in[6];
    const float* rel_bias = (const float*)d_in[7];
    const float* ln_attn_g= (const float*)d_in[8];
    const float* ln_attn_b= (const float*)d_in[9];
    const float* qkv_w    = (const float*)d_in[10];
    const float* qkv_b    = (const float*)d_in[11];
    const float* out_w    = (const float*)d_in[12];
    const float* out_b    = (const float*)d_in[13];
    const float* ln_ff_g  = (const float*)d_in[14];
    const float* ln_ff_b  = (const float*)d_in[15];
    const float* ff1_w    = (const float*)d_in[16];
    const float* ff1_b    = (const float*)d_in[17];
    const float* ff2_w    = (const float*)d_in[18];
    const float* ff2_b    = (const float*)d_in[19];
    const float* fln_g    = (const float*)d_in[20];
    const float* fln_b    = (const float*)d_in[21];
    const float* op_w     = (const float*)d_in[22];
    const float* op_b     = (const float*)d_in[23];
    float* out = (float*)d_out;

    char* ws = (char*)d_ws;
    float*  h     = (float*)(ws);                      //  8,192,000 B
    __bf16* qkvb  = (__bf16*)(ws + 8192000);           // 12,288,000 B
    __bf16* PA    = (__bf16*)(ws + 20480000);          //  4,096,000 B
    __bf16* PBq   = (__bf16*)(ws + 24576000);          //  1,572,864 B
    __bf16* PBo   = (__bf16*)(ws + 26148864);          //    524,288 B
    __bf16* PB1   = (__bf16*)(ws + 26673152);          //  2,097,152 B
    __bf16* PB2   = (__bf16*)(ws + 28770304);          //  2,097,152 B
    __bf16* PBp   = (__bf16*)(ws + 30867456);          //    262,144 B
    __bf16* PBop  = (__bf16*)(ws + 31129600);          //     65,536 B

    // ---- all weight packs, one kernel ----
    k_pack_all<<<1616, 256, 0, stream>>>(qkv_w, out_w, ff1_w, ff2_w, proj_w, op_w,
                                         PBq, PBo, PB1, PB2, PBp, PBop);

    // ---- patch fused (+ qkv for layer 0) ----
    k_patchfused<<<250, 256, 0, stream>>>(x, ln1_g, ln1_b, PBp, proj_b, h,
                                          ln2_g, ln2_b, ln_attn_g, ln_attn_b,
                                          PBq, qkv_b, qkvb);

    for (int l = 0; l < 4; l++) {
        dim3 ag(NB * NHEAD, 8);
        k_attn<<<ag, 256, 0, stream>>>(qkvb, rel_bias, PA);
        // out-proj + residual -> h, LN_ff -> PA
        k_outproj<<<500, 512, 0, stream>>>(PA, PBo + (size_t)l * 65536, out_b + l * 256,
                                           h, PA, ln_ff_g + l * 256, ln_ff_b + l * 256);
        if (l < 3) {
            k_fffused<0><<<500, 512, 0, stream>>>(PA, PB1 + (size_t)l * 262144, ff1_b + l * 1024,
                                                  PB2 + (size_t)l * 262144, ff2_b + l * 256, h,
                                                  ln_attn_g + (l + 1) * 256, ln_attn_b + (l + 1) * 256,
                                                  PBq + (size_t)(l + 1) * 196608, qkv_b + (l + 1) * 768,
                                                  qkvb, nullptr);
        } else {
            k_fffused<1><<<500, 512, 0, stream>>>(PA, PB1 + (size_t)l * 262144, ff1_b + l * 1024,
                                                  PB2 + (size_t)l * 262144, ff2_b + l * 256, h,
                                                  fln_g, fln_b,
                                                  PBop, op_b, nullptr, out);
        }
    }
}

// Round 15
// 280.013 us; speedup vs baseline: 1.2659x; 1.0189x over previous
//
#include <hip/hip_runtime.h>

#define TS 500      // n_patch (sequence length)
#define NB 16       // batch
#define NROW 8000   // NB * TS
#define DMODEL 256
#define NHEAD 8
#define HDIM 32
#define FFD 1024

typedef __bf16 bf16x8 __attribute__((ext_vector_type(8)));
typedef __bf16 bf16x4 __attribute__((ext_vector_type(4)));
typedef float  f32x4  __attribute__((ext_vector_type(4)));
typedef float  f32x2  __attribute__((ext_vector_type(2)));

__device__ __forceinline__ float wred_sum(float v) {
    #pragma unroll
    for (int off = 32; off; off >>= 1) v += __shfl_xor(v, off, 64);
    return v;
}

// A-fragment scatter store (global): element (grow, col) of [8000][K] bf16,
// KS = K/32 fragments per row-tile.
__device__ __forceinline__ void pa_store(__bf16* __restrict__ PA, int KS,
                                         int grow, int col, float y) {
    int mt = grow >> 4, rl = grow & 15;
    size_t idx = ((size_t)(mt * KS + (col >> 5)) * 64 + ((col >> 3) & 3) * 16 + rl) * 8 + (col & 7);
    PA[idx] = (__bf16)y;
}

// A-fragment scatter store (LDS, local row 0..R*16-1, KS=8)
__device__ __forceinline__ void ya_store(__bf16* __restrict__ YA,
                                         int lrow, int col, float y) {
    int mtl = lrow >> 4, rl = lrow & 15;
    int idx = (((mtl * 8 + (col >> 5)) * 64) + ((col >> 3) & 3) * 16 + rl) * 8 + (col & 7);
    YA[idx] = (__bf16)y;
}

// ---------------------------------------------------------------------------
// All weight packs in ONE kernel. Flat grid of 1616 blocks, range dispatch.
// ---------------------------------------------------------------------------
__global__ __launch_bounds__(256) void k_pack_all(
    const float* __restrict__ qkv_w, const float* __restrict__ out_w,
    const float* __restrict__ ff1_w, const float* __restrict__ ff2_w,
    const float* __restrict__ proj_w, const float* __restrict__ op_w,
    __bf16* __restrict__ PBq, __bf16* __restrict__ PBo,
    __bf16* __restrict__ PB1, __bf16* __restrict__ PB2,
    __bf16* __restrict__ PBp, __bf16* __restrict__ PBop)
{
    int bid = blockIdx.x;
    const float* W; __bf16* PB; int KS, NT, wLS, pLS, l, bx;
    if (bid < 384)       { W = qkv_w;  PB = PBq;  KS = 8;  NT = 48; wLS = 196608; pLS = 196608; l = bid / 96;           bx = bid % 96; }
    else if (bid < 512)  { W = out_w;  PB = PBo;  KS = 8;  NT = 16; wLS = 65536;  pLS = 65536;  l = (bid - 384) / 32;   bx = (bid - 384) % 32; }
    else if (bid < 1024) { W = ff1_w;  PB = PB1;  KS = 8;  NT = 64; wLS = 262144; pLS = 262144; l = (bid - 512) / 128;  bx = (bid - 512) % 128; }
    else if (bid < 1536) { W = ff2_w;  PB = PB2;  KS = 32; NT = 16; wLS = 262144; pLS = 262144; l = (bid - 1024) / 128; bx = (bid - 1024) % 128; }
    else if (bid < 1600) { W = proj_w; PB = PBp;  KS = 16; NT = 16; wLS = 0;      pLS = 0;      l = 0;                  bx = bid - 1536; }
    else                 { W = op_w;   PB = PBop; KS = 8;  NT = 8;  wLS = 0;      pLS = 0;      l = 0;                  bx = bid - 1600; }

    int gid = bx * 256 + threadIdx.x;
    if (gid >= NT * KS * 64) return;
    int lane = gid & 63;
    int ks = (gid >> 6) % KS;
    int nt = (gid >> 6) / KS;
    int N = NT * 16;
    int k0 = ks * 32 + (lane >> 4) * 8;
    int col = nt * 16 + (lane & 15);
    const float* src = W + (size_t)l * wLS;
    bf16x8 v;
    #pragma unroll
    for (int j = 0; j < 8; j++) v[j] = (__bf16)src[(size_t)(k0 + j) * N + col];
    *(bf16x8*)(PB + (size_t)l * pLS + ((size_t)(nt * KS + ks) * 64 + lane) * 8) = v;
}

// ---------------------------------------------------------------------------
// Patch stage FUSED + qkv[0] (unchanged, passing).
// ---------------------------------------------------------------------------
__global__ __launch_bounds__(256) void k_patchfused(
    const float* __restrict__ x, const float* __restrict__ g1, const float* __restrict__ b1,
    const __bf16* __restrict__ PBp, const float* __restrict__ bias,
    float* __restrict__ h,
    const float* __restrict__ gam, const float* __restrict__ bet,
    const float* __restrict__ gam2, const float* __restrict__ bet2,
    const __bf16* __restrict__ PBq0, const float* __restrict__ qb0,
    __bf16* __restrict__ qkvb)
{
    __shared__ __align__(16) __bf16 As[2][16][64][8];   // 32 KB; reused as YA
    __shared__ float redS[4][32];
    __shared__ float redQ[4][32];
    int t = threadIdx.x, lane = t & 63, w = t >> 6;
    int row0 = blockIdx.x * 32;

    for (int rr = 0; rr < 8; rr++) {
        int lrow = w * 8 + rr;
        int row = row0 + lrow;
        int b = row / TS, pp = row - b * TS;
        int kb = lane * 8;
        const float* src = x + ((size_t)(pp * 4 + (kb >> 7)) * NB + b) * 128 + (kb & 127);
        float4 lo = *(const float4*)src;
        float4 hi = *(const float4*)(src + 4);
        float v[8] = {lo.x, lo.y, lo.z, lo.w, hi.x, hi.y, hi.z, hi.w};
        float sm_ = 0.f;
        #pragma unroll
        for (int j = 0; j < 8; j++) sm_ += v[j];
        sm_ = wred_sum(sm_);
        float mu = sm_ * (1.0f / 512.0f);
        float q = 0.f;
        #pragma unroll
        for (int j = 0; j < 8; j++) { float d = v[j] - mu; q += d * d; }
        q = wred_sum(q);
        float rs = rsqrtf(q * (1.0f / 512.0f) + 1e-6f);
        float4 gl = *(const float4*)(g1 + kb), gh = *(const float4*)(g1 + kb + 4);
        float4 bl = *(const float4*)(b1 + kb), bh = *(const float4*)(b1 + kb + 4);
        float gg[8] = {gl.x, gl.y, gl.z, gl.w, gh.x, gh.y, gh.z, gh.w};
        float bbv[8] = {bl.x, bl.y, bl.z, bl.w, bh.x, bh.y, bh.z, bh.w};
        bf16x8 yv;
        #pragma unroll
        for (int j = 0; j < 8; j++) yv[j] = (__bf16)((v[j] - mu) * rs * gg[j] + bbv[j]);
        *(bf16x8*)&As[lrow >> 4][lane >> 2][(lane & 3) * 16 + (lrow & 15)][0] = yv;
    }
    __syncthreads();

    const bf16x8* B8 = (const bf16x8*)PBp;
    f32x4 acc[2][4] = {};
    #pragma unroll 8
    for (int ks = 0; ks < 16; ks++) {
        bf16x8 a0 = *(const bf16x8*)&As[0][ks][lane][0];
        bf16x8 a1 = *(const bf16x8*)&As[1][ks][lane][0];
        #pragma unroll
        for (int n = 0; n < 4; n++) {
            bf16x8 b = B8[((size_t)(w * 4 + n) * 16 + ks) * 64 + lane];
            acc[0][n] = __builtin_amdgcn_mfma_f32_16x16x32_bf16(a0, b, acc[0][n], 0, 0, 0);
            acc[1][n] = __builtin_amdgcn_mfma_f32_16x16x32_bf16(a1, b, acc[1][n], 0, 0, 0);
        }
    }

    int g_ = lane >> 4, cl = lane & 15;
    int rbase = g_ * 4;
    float gamv[4], betv[4], gam2v[4], bet2v[4];
    #pragma unroll
    for (int n = 0; n < 4; n++) {
        int col = (w * 4 + n) * 16 + cl;
        float bv = bias[col];
        gamv[n] = gam[col]; betv[n] = bet[col];
        gam2v[n] = gam2[col]; bet2v[n] = bet2[col];
        #pragma unroll
        for (int m = 0; m < 2; m++)
            #pragma unroll
            for (int r = 0; r < 4; r++) acc[m][n][r] += bv;
    }
    float mu[2][4], rstd[2][4];
    {
        float ps[2][4];
        #pragma unroll
        for (int m = 0; m < 2; m++)
            #pragma unroll
            for (int r = 0; r < 4; r++) {
                float s2 = acc[m][0][r] + acc[m][1][r] + acc[m][2][r] + acc[m][3][r];
                #pragma unroll
                for (int off = 1; off < 16; off <<= 1) s2 += __shfl_xor(s2, off, 64);
                ps[m][r] = s2;
            }
        if (cl == 0)
            #pragma unroll
            for (int m = 0; m < 2; m++)
                #pragma unroll
                for (int r = 0; r < 4; r++) redS[w][m * 16 + rbase + r] = ps[m][r];
        __syncthreads();
        #pragma unroll
        for (int m = 0; m < 2; m++)
            #pragma unroll
            for (int r = 0; r < 4; r++) {
                int lr = m * 16 + rbase + r;
                mu[m][r] = (redS[0][lr] + redS[1][lr] + redS[2][lr] + redS[3][lr]) * (1.0f / 256.0f);
            }
        float pq[2][4];
        #pragma unroll
        for (int m = 0; m < 2; m++)
            #pragma unroll
            for (int r = 0; r < 4; r++) {
                float s2 = 0.f;
                #pragma unroll
                for (int n = 0; n < 4; n++) { float d = acc[m][n][r] - mu[m][r]; s2 += d * d; }
                #pragma unroll
                for (int off = 1; off < 16; off <<= 1) s2 += __shfl_xor(s2, off, 64);
                pq[m][r] = s2;
            }
        if (cl == 0)
            #pragma unroll
            for (int m = 0; m < 2; m++)
                #pragma unroll
                for (int r = 0; r < 4; r++) redQ[w][m * 16 + rbase + r] = pq[m][r];
        __syncthreads();
        #pragma unroll
        for (int m = 0; m < 2; m++)
            #pragma unroll
            for (int r = 0; r < 4; r++) {
                int lr = m * 16 + rbase + r;
                float var = (redQ[0][lr] + redQ[1][lr] + redQ[2][lr] + redQ[3][lr]) * (1.0f / 256.0f);
                rstd[m][r] = rsqrtf(var + 1e-6f);
            }
    }
    float ps2[2][4];
    #pragma unroll
    for (int m = 0; m < 2; m++) {
        int row = row0 + m * 16 + rbase;
        #pragma unroll
        for (int r = 0; r < 4; r++) {
            float s2 = 0.f;
            #pragma unroll
            for (int n = 0; n < 4; n++) {
                int col = (w * 4 + n) * 16 + cl;
                float y1 = (acc[m][n][r] - mu[m][r]) * rstd[m][r] * gamv[n] + betv[n];
                h[(size_t)(row + r) * 256 + col] = y1;
                s2 += y1;
            }
            #pragma unroll
            for (int off = 1; off < 16; off <<= 1) s2 += __shfl_xor(s2, off, 64);
            ps2[m][r] = s2;
        }
    }
    if (cl == 0)
        #pragma unroll
        for (int m = 0; m < 2; m++)
            #pragma unroll
            for (int r = 0; r < 4; r++) redS[w][m * 16 + rbase + r] = ps2[m][r];
    __syncthreads();
    float mu2[2][4], rstd2[2][4];
    #pragma unroll
    for (int m = 0; m < 2; m++)
        #pragma unroll
        for (int r = 0; r < 4; r++) {
            int lr = m * 16 + rbase + r;
            mu2[m][r] = (redS[0][lr] + redS[1][lr] + redS[2][lr] + redS[3][lr]) * (1.0f / 256.0f);
        }
    float pq2[2][4];
    #pragma unroll
    for (int m = 0; m < 2; m++)
        #pragma unroll
        for (int r = 0; r < 4; r++) {
            float s2 = 0.f;
            #pragma unroll
            for (int n = 0; n < 4; n++) {
                float y1 = (acc[m][n][r] - mu[m][r]) * rstd[m][r] * gamv[n] + betv[n];
                float d = y1 - mu2[m][r];
                s2 += d * d;
            }
            #pragma unroll
            for (int off = 1; off < 16; off <<= 1) s2 += __shfl_xor(s2, off, 64);
            pq2[m][r] = s2;
        }
    if (cl == 0)
        #pragma unroll
        for (int m = 0; m < 2; m++)
            #pragma unroll
            for (int r = 0; r < 4; r++) redQ[w][m * 16 + rbase + r] = pq2[m][r];
    __syncthreads();
    #pragma unroll
    for (int m = 0; m < 2; m++)
        #pragma unroll
        for (int r = 0; r < 4; r++) {
            int lr = m * 16 + rbase + r;
            float var = (redQ[0][lr] + redQ[1][lr] + redQ[2][lr] + redQ[3][lr]) * (1.0f / 256.0f);
            rstd2[m][r] = rsqrtf(var + 1e-5f);
        }
    __bf16* YA = &As[0][0][0][0];   // [2][8][64][8]
    #pragma unroll
    for (int m = 0; m < 2; m++) {
        #pragma unroll
        for (int n = 0; n < 4; n++) {
            int col = (w * 4 + n) * 16 + cl;
            #pragma unroll
            for (int r = 0; r < 4; r++) {
                float y1 = (acc[m][n][r] - mu[m][r]) * rstd[m][r] * gamv[n] + betv[n];
                float y2 = (y1 - mu2[m][r]) * rstd2[m][r] * gam2v[n] + bet2v[n];
                ya_store(YA, m * 16 + rbase + r, col, y2);
            }
        }
    }
    __syncthreads();

    const bf16x8* YA8 = (const bf16x8*)YA;
    const bf16x8* B8q = (const bf16x8*)PBq0;
    for (int m = 0; m < 2; m++) {
        f32x4 acc2[12] = {};
        for (int ks = 0; ks < 8; ks++) {
            bf16x8 a = YA8[(m * 8 + ks) * 64 + lane];
            #pragma unroll
            for (int n = 0; n < 12; n++) {
                bf16x8 b = B8q[((size_t)(w * 12 + n) * 8 + ks) * 64 + lane];
                acc2[n] = __builtin_amdgcn_mfma_f32_16x16x32_bf16(a, b, acc2[n], 0, 0, 0);
            }
        }
        int row = row0 + m * 16 + rbase;
        #pragma unroll
        for (int n = 0; n < 12; n++) {
            int col = (w * 12 + n) * 16 + cl;
            float bv = qb0[col];
            #pragma unroll
            for (int r = 0; r < 4; r++)
                qkvb[(size_t)(row + r) * 768 + col] = (__bf16)(acc2[n][r] + bv);
        }
    }
}

// ---------------------------------------------------------------------------
// Out-projection GEMM (EPI4), 512 threads / 8 waves (unchanged, passing).
// ---------------------------------------------------------------------------
__global__ __launch_bounds__(512) void k_outproj(
    const __bf16* __restrict__ PA, const __bf16* __restrict__ PB,
    const float* __restrict__ bias, float* __restrict__ dst,
    __bf16* __restrict__ dstb,
    const float* __restrict__ gam, const float* __restrict__ bet)
{
    __shared__ float redS[8][16];
    __shared__ float redQ[8][16];
    int t = threadIdx.x, lane = t & 63, w = t >> 6;   // w in 0..7
    int mt0 = blockIdx.x;

    const bf16x8* A8 = (const bf16x8*)PA;
    const bf16x8* B8 = (const bf16x8*)PB;

    f32x4 acc[2] = {};
    #pragma unroll 8
    for (int ks = 0; ks < 8; ks++) {
        bf16x8 a = A8[((size_t)mt0 * 8 + ks) * 64 + lane];
        #pragma unroll
        for (int n = 0; n < 2; n++) {
            bf16x8 b = B8[((size_t)(w * 2 + n) * 8 + ks) * 64 + lane];
            acc[n] = __builtin_amdgcn_mfma_f32_16x16x32_bf16(a, b, acc[n], 0, 0, 0);
        }
    }

    int g_ = lane >> 4, cl = lane & 15;
    int rbase = g_ * 4;
    float gamv[2], betv[2];
    #pragma unroll
    for (int n = 0; n < 2; n++) {
        int col = (w * 2 + n) * 16 + cl;
        float bv = bias[col];
        gamv[n] = gam[col]; betv[n] = bet[col];
        int row = mt0 * 16 + rbase;
        #pragma unroll
        for (int r = 0; r < 4; r++) {
            float v = acc[n][r] + bv + dst[(size_t)(row + r) * 256 + col];
            dst[(size_t)(row + r) * 256 + col] = v;
            acc[n][r] = v;
        }
    }
    float mu[4], rstd[4];
    {
        float ps[4];
        #pragma unroll
        for (int r = 0; r < 4; r++) {
            float s2 = acc[0][r] + acc[1][r];
            #pragma unroll
            for (int off = 1; off < 16; off <<= 1) s2 += __shfl_xor(s2, off, 64);
            ps[r] = s2;
        }
        if (cl == 0)
            #pragma unroll
            for (int r = 0; r < 4; r++) redS[w][rbase + r] = ps[r];
        __syncthreads();
        #pragma unroll
        for (int r = 0; r < 4; r++) {
            int lr = rbase + r;
            float s2 = 0.f;
            #pragma unroll
            for (int ww = 0; ww < 8; ww++) s2 += redS[ww][lr];
            mu[r] = s2 * (1.0f / 256.0f);
        }
        float pq[4];
        #pragma unroll
        for (int r = 0; r < 4; r++) {
            float s2 = 0.f;
            #pragma unroll
            for (int n = 0; n < 2; n++) { float d = acc[n][r] - mu[r]; s2 += d * d; }
            #pragma unroll
            for (int off = 1; off < 16; off <<= 1) s2 += __shfl_xor(s2, off, 64);
            pq[r] = s2;
        }
        if (cl == 0)
            #pragma unroll
            for (int r = 0; r < 4; r++) redQ[w][rbase + r] = pq[r];
        __syncthreads();
        #pragma unroll
        for (int r = 0; r < 4; r++) {
            int lr = rbase + r;
            float s2 = 0.f;
            #pragma unroll
            for (int ww = 0; ww < 8; ww++) s2 += redQ[ww][lr];
            rstd[r] = rsqrtf(s2 * (1.0f / 256.0f) + 1e-5f);
        }
    }
    int row = mt0 * 16 + rbase;
    #pragma unroll
    for (int n = 0; n < 2; n++) {
        int col = (w * 2 + n) * 16 + cl;
        #pragma unroll
        for (int r = 0; r < 4; r++) {
            float y = (acc[n][r] - mu[r]) * rstd[r] * gamv[n] + betv[n];
            pa_store(dstb, 8, row + r, col, y);
        }
    }
}

// ---------------------------------------------------------------------------
// FF block FUSED + next GEMM, 512 threads / 8 waves (unchanged, passing).
// ---------------------------------------------------------------------------
template<int MODE>
__global__ __launch_bounds__(512) void k_fffused(
    const __bf16* __restrict__ PA, const __bf16* __restrict__ PB1,
    const float* __restrict__ b1, const __bf16* __restrict__ PB2,
    const float* __restrict__ b2, float* __restrict__ h,
    const float* __restrict__ gam, const float* __restrict__ bet,
    const __bf16* __restrict__ PBn, const float* __restrict__ bn,
    __bf16* __restrict__ qkvb, float* __restrict__ outp)
{
    __shared__ __align__(16) __bf16 F1T[1024][16];   // 32 KB; head reused as YA
    __shared__ float redS[8][16];
    __shared__ float redQ[8][16];
    int t = threadIdx.x, lane = t & 63, w = t >> 6;  // w in 0..7
    int mt = blockIdx.x;
    int g_ = lane >> 4, cl = lane & 15, rbase = g_ * 4;

    const bf16x8* A8 = (const bf16x8*)PA;
    const bf16x8* B81 = (const bf16x8*)PB1;
    const bf16x8* B82 = (const bf16x8*)PB2;

    // ---- Phase A: ff1, wave w covers cols [w*128, w*128+128) ----
    f32x4 acc1[8] = {};
    #pragma unroll 2
    for (int ks = 0; ks < 8; ks++) {
        bf16x8 a = A8[((size_t)mt * 8 + ks) * 64 + lane];
        #pragma unroll
        for (int n = 0; n < 8; n++) {
            bf16x8 b = B81[((size_t)(w * 8 + n) * 8 + ks) * 64 + lane];
            acc1[n] = __builtin_amdgcn_mfma_f32_16x16x32_bf16(a, b, acc1[n], 0, 0, 0);
        }
    }
    #pragma unroll
    for (int n = 0; n < 8; n++) {
        int col = (w * 8 + n) * 16 + cl;
        float bv = b1[col];
        bf16x4 pv;
        #pragma unroll
        for (int r = 0; r < 4; r++) {
            float xx = acc1[n][r] + bv;
            pv[r] = (__bf16)(0.5f * xx * (1.0f + erff(xx * 0.70710678118654752f)));
        }
        *(bf16x4*)&F1T[col][rbase] = pv;
    }
    __syncthreads();

    // ---- Phase B: ff2, K=1024; A-frags via tr_b16; wave owns 2 n-tiles ----
    f32x4 acc[2] = {};
    for (int kb = 0; kb < 8; kb++) {
        f32x2 lo[4], hi[4];
        #pragma unroll
        for (int q = 0; q < 4; q++) {
            unsigned ta = (unsigned)(uintptr_t)&F1T[(kb * 4 + q) * 32 + 8 * g_][0] + cl * 8;
            asm volatile("ds_read_b64_tr_b16 %0, %1" : "=v"(lo[q]) : "v"(ta) : "memory");
            asm volatile("ds_read_b64_tr_b16 %0, %1 offset:128" : "=v"(hi[q]) : "v"(ta) : "memory");
        }
        asm volatile("s_waitcnt lgkmcnt(0)" ::: "memory");
        __builtin_amdgcn_sched_barrier(0);
        #pragma unroll
        for (int q = 0; q < 4; q++) {
            int ks = kb * 4 + q;
            f32x4 pc = {lo[q][0], lo[q][1], hi[q][0], hi[q][1]};
            bf16x8 a = __builtin_bit_cast(bf16x8, pc);
            #pragma unroll
            for (int n = 0; n < 2; n++) {
                bf16x8 b = B82[((size_t)(w * 2 + n) * 32 + ks) * 64 + lane];
                acc[n] = __builtin_amdgcn_mfma_f32_16x16x32_bf16(a, b, acc[n], 0, 0, 0);
            }
        }
    }

    // ---- EPI: +b2, residual -> h, LN -> YA (LDS) ----
    float gamv[2], betv[2];
    #pragma unroll
    for (int n = 0; n < 2; n++) {
        int col = (w * 2 + n) * 16 + cl;
        float bv = b2[col];
        gamv[n] = gam[col]; betv[n] = bet[col];
        int row = mt * 16 + rbase;
        #pragma unroll
        for (int r = 0; r < 4; r++) {
            float v = acc[n][r] + bv + h[(size_t)(row + r) * 256 + col];
            h[(size_t)(row + r) * 256 + col] = v;
            acc[n][r] = v;
        }
    }
    float mu[4], rstd[4];
    {
        float ps[4];
        #pragma unroll
        for (int r = 0; r < 4; r++) {
            float s2 = acc[0][r] + acc[1][r];
            #pragma unroll
            for (int off = 1; off < 16; off <<= 1) s2 += __shfl_xor(s2, off, 64);
            ps[r] = s2;
        }
        if (cl == 0)
            #pragma unroll
            for (int r = 0; r < 4; r++) redS[w][rbase + r] = ps[r];
        __syncthreads();
        #pragma unroll
        for (int r = 0; r < 4; r++) {
            int lr = rbase + r;
            float s2 = 0.f;
            #pragma unroll
            for (int ww = 0; ww < 8; ww++) s2 += redS[ww][lr];
            mu[r] = s2 * (1.0f / 256.0f);
        }
        float pq[4];
        #pragma unroll
        for (int r = 0; r < 4; r++) {
            float s2 = 0.f;
            #pragma unroll
            for (int n = 0; n < 2; n++) { float d = acc[n][r] - mu[r]; s2 += d * d; }
            #pragma unroll
            for (int off = 1; off < 16; off <<= 1) s2 += __shfl_xor(s2, off, 64);
            pq[r] = s2;
        }
        if (cl == 0)
            #pragma unroll
            for (int r = 0; r < 4; r++) redQ[w][rbase + r] = pq[r];
        __syncthreads();   // also guarantees all waves done reading F1T
        #pragma unroll
        for (int r = 0; r < 4; r++) {
            int lr = rbase + r;
            float s2 = 0.f;
            #pragma unroll
            for (int ww = 0; ww < 8; ww++) s2 += redQ[ww][lr];
            rstd[r] = rsqrtf(s2 * (1.0f / 256.0f) + 1e-5f);
        }
    }
    // y -> LDS A-frags (reuse F1T head: [8][64][8] = 8 KB)
    __bf16* YA = &F1T[0][0];
    #pragma unroll
    for (int n = 0; n < 2; n++) {
        int col = (w * 2 + n) * 16 + cl;
        #pragma unroll
        for (int r = 0; r < 4; r++) {
            float y = (acc[n][r] - mu[r]) * rstd[r] * gamv[n] + betv[n];
            ya_store(YA, rbase + r, col, y);
        }
    }
    __syncthreads();

    // ---- tail GEMM from YA ----
    const bf16x8* YA8 = (const bf16x8*)YA;
    const bf16x8* B8n = (const bf16x8*)PBn;
    if constexpr (MODE == 0) {
        // qkv[l+1]: 48 n-tiles, wave owns 6
        f32x4 acc2[6] = {};
        for (int ks = 0; ks < 8; ks++) {
            bf16x8 a = YA8[ks * 64 + lane];
            #pragma unroll
            for (int n = 0; n < 6; n++) {
                bf16x8 b = B8n[((size_t)(w * 6 + n) * 8 + ks) * 64 + lane];
                acc2[n] = __builtin_amdgcn_mfma_f32_16x16x32_bf16(a, b, acc2[n], 0, 0, 0);
            }
        }
        int row = mt * 16 + rbase;
        #pragma unroll
        for (int n = 0; n < 6; n++) {
            int col = (w * 6 + n) * 16 + cl;
            float bv = bn[col];
            #pragma unroll
            for (int r = 0; r < 4; r++)
                qkvb[(size_t)(row + r) * 768 + col] = (__bf16)(acc2[n][r] + bv);
        }
    } else {
        // final projection: 8 n-tiles, wave owns 1; swapaxes write
        f32x4 acc2 = {};
        #pragma unroll 4
        for (int ks = 0; ks < 8; ks++) {
            bf16x8 a = YA8[ks * 64 + lane];
            bf16x8 b = B8n[((size_t)w * 8 + ks) * 64 + lane];
            acc2 = __builtin_amdgcn_mfma_f32_16x16x32_bf16(a, b, acc2, 0, 0, 0);
        }
        int row = mt * 16 + rbase;
        int col = w * 16 + cl;
        float bv = bn[col];
        #pragma unroll
        for (int r = 0; r < 4; r++) {
            int grow = row + r;
            int bq = grow / TS, pp = grow - bq * TS;
            outp[((size_t)pp * NB + bq) * 128 + col] = acc2[r] + bv;
        }
    }
}

// ---------------------------------------------------------------------------
// MFMA flash attention, qt-PAIRED: 512 threads / 8 waves per block.
// Waves 0-3 handle qt_hi = 2*pr+1, waves 4-7 handle qt_lo = 2*pr; K/V
// staging shared (waves 0-3 stage K B-frags, waves 4-7 stage V planes).
// Lower group skips compute (keeps barriers) once j exceeds its range.
// Grid (128 bh, 4 pairs), heavy pairs first. LDS ~25 KB.
// ---------------------------------------------------------------------------
__global__ __launch_bounds__(512) void k_attn(
    const __bf16* __restrict__ qkv, const float* __restrict__ rel_bias,
    __bf16* __restrict__ PA)
{
    __shared__ __align__(16) __bf16 Kfr[4][64][8];
    __shared__ __align__(16) __bf16 Vpl[2][64][16];
    __shared__ __align__(16) __bf16 PT[8][64][16];
    __shared__ float bias_s[132];

    int bh = blockIdx.x;
    int pr = 3 - blockIdx.y;                 // heavy pairs first
    int b = bh >> 3, hh = bh & 7;
    int t = threadIdx.x, lane = t & 63, w = t >> 6;   // w in 0..7
    int wg = w & 3, grp = w >> 2;            // grp 0 -> qt_hi, grp 1 -> qt_lo
    int qt = 2 * pr + 1 - grp;
    int q0 = qt * 64 + wg * 16;              // this wave's 16-query m-tile
    int c = lane & 15, g = lane >> 4;

    const __bf16* base = qkv + (size_t)b * TS * 768 + hh * 32;

    if (t < 129) bias_s[t] = rel_bias[hh * 129 + t];

    bf16x8 aq = {};
    {
        int qi = q0 + c;
        if (qi < TS) aq = *(const bf16x8*)(base + (size_t)qi * 768 + 8 * g);
    }

    float lpart[4] = {0.f, 0.f, 0.f, 0.f};
    f32x4 O0 = {}, O1 = {};
    const float scale = 0.17677669529663687f;

    int nj = 2 * pr + 2;

    for (int it = 0; it < nj; it++) {
        int j0 = it * 64;
        __syncthreads();
        if (w < 4) {
            // K staging: wave w stages B-frag tile jt = w
            int j = j0 + w * 16 + c;
            bf16x8 kv = {};
            if (j < TS) kv = *(const bf16x8*)(base + (size_t)j * 768 + 256 + 8 * g);
            *(bf16x8*)&Kfr[w][lane][0] = kv;
        } else {
            // V staging: threads 256..511
            int t2 = t - 256;
            int jl = t2 >> 2, dseg = t2 & 3;
            int j = j0 + jl;
            bf16x8 vv = {};
            if (j < TS) vv = *(const bf16x8*)(base + (size_t)j * 768 + 512 + 8 * dseg);
            *(bf16x8*)&Vpl[dseg >> 1][jl][(dseg & 1) * 8] = vv;
        }
        __syncthreads();

        if (it > qt) continue;   // this wave-group done; barriers stay uniform

        f32x4 S[4];
        f32x4 zero = {};
        #pragma unroll
        for (int jt = 0; jt < 4; jt++) {
            bf16x8 bk = *(const bf16x8*)&Kfr[jt][lane][0];
            S[jt] = __builtin_amdgcn_mfma_f32_16x16x32_bf16(aq, bk, zero, 0, 0, 0);
        }

        #pragma unroll
        for (int jt = 0; jt < 4; jt++) {
            int j = j0 + jt * 16 + c;
            #pragma unroll
            for (int r = 0; r < 4; r++) {
                int i = q0 + 4 * g + r;
                int rel = j - i;
                rel = rel < -64 ? -64 : (rel > 64 ? 64 : rel);
                float sv = S[jt][r] * scale + bias_s[rel + 64];
                float pr_ = (j > i) ? 0.f : __expf(sv);
                S[jt][r] = pr_;
                lpart[r] += pr_;
            }
        }

        #pragma unroll
        for (int jt = 0; jt < 4; jt++) {
            bf16x4 pv;
            pv[0] = (__bf16)S[jt][0]; pv[1] = (__bf16)S[jt][1];
            pv[2] = (__bf16)S[jt][2]; pv[3] = (__bf16)S[jt][3];
            *(bf16x4*)&PT[w][jt * 16 + c][4 * g] = pv;
        }
        asm volatile("s_waitcnt lgkmcnt(0)" ::: "memory");
        __builtin_amdgcn_sched_barrier(0);

        f32x2 pa_lo[2], pa_hi[2], vb_lo[2][2], vb_hi[2][2];
        #pragma unroll
        for (int jb = 0; jb < 2; jb++) {
            unsigned pta = (unsigned)(uintptr_t)&PT[w][jb * 32 + 8 * g][0] + c * 8;
            asm volatile("ds_read_b64_tr_b16 %0, %1" : "=v"(pa_lo[jb]) : "v"(pta) : "memory");
            asm volatile("ds_read_b64_tr_b16 %0, %1 offset:128" : "=v"(pa_hi[jb]) : "v"(pta) : "memory");
            #pragma unroll
            for (int dh = 0; dh < 2; dh++) {
                unsigned vta = (unsigned)(uintptr_t)&Vpl[dh][jb * 32 + 8 * g][0] + c * 8;
                asm volatile("ds_read_b64_tr_b16 %0, %1" : "=v"(vb_lo[jb][dh]) : "v"(vta) : "memory");
                asm volatile("ds_read_b64_tr_b16 %0, %1 offset:128" : "=v"(vb_hi[jb][dh]) : "v"(vta) : "memory");
            }
        }
        asm volatile("s_waitcnt lgkmcnt(0)" ::: "memory");
        __builtin_amdgcn_sched_barrier(0);

        #pragma unroll
        for (int jb = 0; jb < 2; jb++) {
            f32x4 pc = {pa_lo[jb][0], pa_lo[jb][1], pa_hi[jb][0], pa_hi[jb][1]};
            bf16x8 pa = __builtin_bit_cast(bf16x8, pc);
            f32x4 v0c = {vb_lo[jb][0][0], vb_lo[jb][0][1], vb_hi[jb][0][0], vb_hi[jb][0][1]};
            f32x4 v1c = {vb_lo[jb][1][0], vb_lo[jb][1][1], vb_hi[jb][1][0], vb_hi[jb][1][1]};
            bf16x8 vb0 = __builtin_bit_cast(bf16x8, v0c);
            bf16x8 vb1 = __builtin_bit_cast(bf16x8, v1c);
            O0 = __builtin_amdgcn_mfma_f32_16x16x32_bf16(pa, vb0, O0, 0, 0, 0);
            O1 = __builtin_amdgcn_mfma_f32_16x16x32_bf16(pa, vb1, O1, 0, 0, 0);
        }
    }

    #pragma unroll
    for (int r = 0; r < 4; r++) {
        #pragma unroll
        for (int off = 1; off < 16; off <<= 1) lpart[r] += __shfl_xor(lpart[r], off, 64);
    }
    #pragma unroll
    for (int r = 0; r < 4; r++) {
        int i = q0 + 4 * g + r;
        if (i < TS) {
            float inv = 1.0f / lpart[r];
            int grow = b * TS + i;
            int mt = grow >> 4, rl = grow & 15;
            size_t fb = (size_t)(mt * 8 + hh) * 64;
            PA[(fb + ((c >> 3) & 1) * 16 + rl) * 8 + (c & 7)]       = (__bf16)(O0[r] * inv);
            PA[(fb + (2 + ((c >> 3) & 1)) * 16 + rl) * 8 + (c & 7)] = (__bf16)(O1[r] * inv);
        }
    }
}

extern "C" void kernel_launch(void* const* d_in, const int* in_sizes, int n_in,
                              void* d_out, int out_size, void* d_ws, size_t ws_size,
                              hipStream_t stream)
{
    const float* x        = (const float*)d_in[0];
    const float* ln1_g    = (const float*)d_in[1];
    const float* ln1_b    = (const float*)d_in[2];
    const float* proj_w   = (const float*)d_in[3];
    const float* proj_b   = (const float*)d_in[4];
    const float* ln2_g    = (const float*)d_in[5];
    const float* ln2_b    = (const float*)d_in[6];
    const float* rel_bias = (const float*)d_in[7];
    const float* ln_attn_g= (const float*)d_in[8];
    const float* ln_attn_b= (const float*)d_in[9];
    const float* qkv_w    = (const float*)d_in[10];
    const float* qkv_b    = (const float*)d_in[11];
    const float* out_w    = (const float*)d_in[12];
    const float* out_b    = (const float*)d_in[13];
    const float* ln_ff_g  = (const float*)d_in[14];
    const float* ln_ff_b  = (const float*)d_in[15];
    const float* ff1_w    = (const float*)d_in[16];
    const float* ff1_b    = (const float*)d_in[17];
    const float* ff2_w    = (const float*)d_in[18];
    const float* ff2_b    = (const float*)d_in[19];
    const float* fln_g    = (const float*)d_in[20];
    const float* fln_b    = (const float*)d_in[21];
    const float* op_w     = (const float*)d_in[22];
    const float* op_b     = (const float*)d_in[23];
    float* out = (float*)d_out;

    char* ws = (char*)d_ws;
    float*  h     = (float*)(ws);                      //  8,192,000 B
    __bf16* qkvb  = (__bf16*)(ws + 8192000);           // 12,288,000 B
    __bf16* PA    = (__bf16*)(ws + 20480000);          //  4,096,000 B
    __bf16* PBq   = (__bf16*)(ws + 24576000);          //  1,572,864 B
    __bf16* PBo   = (__bf16*)(ws + 26148864);          //    524,288 B
    __bf16* PB1   = (__bf16*)(ws + 26673152);          //  2,097,152 B
    __bf16* PB2   = (__bf16*)(ws + 28770304);          //  2,097,152 B
    __bf16* PBp   = (__bf16*)(ws + 30867456);          //    262,144 B
    __bf16* PBop  = (__bf16*)(ws + 31129600);          //     65,536 B

    // ---- all weight packs, one kernel ----
    k_pack_all<<<1616, 256, 0, stream>>>(qkv_w, out_w, ff1_w, ff2_w, proj_w, op_w,
                                         PBq, PBo, PB1, PB2, PBp, PBop);

    // ---- patch fused (+ qkv for layer 0) ----
    k_patchfused<<<250, 256, 0, stream>>>(x, ln1_g, ln1_b, PBp, proj_b, h,
                                          ln2_g, ln2_b, ln_attn_g, ln_attn_b,
                                          PBq, qkv_b, qkvb);

    for (int l = 0; l < 4; l++) {
        dim3 ag(NB * NHEAD, 4);
        k_attn<<<ag, 512, 0, stream>>>(qkvb, rel_bias, PA);
        // out-proj + residual -> h, LN_ff -> PA
        k_outproj<<<500, 512, 0, stream>>>(PA, PBo + (size_t)l * 65536, out_b + l * 256,
                                           h, PA, ln_ff_g + l * 256, ln_ff_b + l * 256);
        if (l < 3) {
            k_fffused<0><<<500, 512, 0, stream>>>(PA, PB1 + (size_t)l * 262144, ff1_b + l * 1024,
                                                  PB2 + (size_t)l * 262144, ff2_b + l * 256, h,
                                                  ln_attn_g + (l + 1) * 256, ln_attn_b + (l + 1) * 256,
                                                  PBq + (size_t)(l + 1) * 196608, qkv_b + (l + 1) * 768,
                                                  qkvb, nullptr);
        } else {
            k_fffused<1><<<500, 512, 0, stream>>>(PA, PB1 + (size_t)l * 262144, ff1_b + l * 1024,
                                                  PB2 + (size_t)l * 262144, ff2_b + l * 256, h,
                                                  fln_g, fln_b,
                                                  PBop, op_b, nullptr, out);
        }
    }
}